// Round 2
// baseline (678.475 us; speedup 1.0000x reference)
//
#include <hip/hip_runtime.h>

#pragma clang fp contract(off)

typedef unsigned int u32;
typedef unsigned long long u64;

#define N_ROWS 32768
#define NCLS 81
#define TOPK 4096
#define MAXCAND 327680
#define EQCAP 8192
#define IMGW_M1 1332.0f
#define IMGH_M1 799.0f

// ---------------- ws layout (u32 units) ----------------
// [0,16)                     cnt: 0=candCount 1=selCount 2=eqCount 3=hiBin 4=countAboveHi 5=cutKey 6=numFromEqual
// [16, 16+65536)             hist1
// [+65536)                   hist2
// [131088, +8192)            sel (u64[4096])
// [139280, +MAXCAND)         candKey
// [+MAXCAND)                 candIdx
// [+EQCAP)                   eqIdx
// [+16384)                   rboxes (f32 4096x4)
// [+4096)                    rvals
// [+4096)                    rlabel (i32)

__global__ void k_zero(u32* __restrict__ p, int n) {
    int i = blockIdx.x * blockDim.x + threadIdx.x;
    if (i < n) p[i] = 0u;
}

// softmax per row (f64 accumulate: error ~1e-16 << ref's f32 error, so our
// ordering == true ordering; ref's f32 rounding is monotone so it can only
// tie, not reverse, vs truth) + threshold filter + hi-16 histogram
__global__ void k_cand(const float* __restrict__ x, u32* __restrict__ candKey,
                       u32* __restrict__ candIdx, u32* __restrict__ cnt,
                       u32* __restrict__ hist1) {
    int r = blockIdx.x * blockDim.x + threadIdx.x;
    if (r >= N_ROWS) return;
    const float* xr = x + (size_t)r * NCLS;
    float m = xr[0];
    for (int c = 1; c < NCLS; c++) m = fmaxf(m, xr[c]);
    double s = 0.0;
    for (int c = 0; c < NCLS; c++) {
        float d = xr[c] - m;             // f32 subtract, same as reference
        s += exp((double)d);
    }
    for (int c = 1; c < NCLS; c++) {     // class 0 excluded
        float d = xr[c] - m;
        double p = exp((double)d) / s;
        float pf = (float)p;             // correctly-rounded true probability
        if (pf > 0.05f) {
            u32 pos = atomicAdd(&cnt[0], 1u);
            if (pos < MAXCAND) {
                u32 key = __float_as_uint(pf); // positive floats: bits order-isomorphic
                candKey[pos] = key;
                candIdx[pos] = (u32)(r * NCLS + c);
                atomicAdd(&hist1[key >> 16], 1u);
            }
        }
    }
}

__global__ void __launch_bounds__(1024) k_cut1(const u32* __restrict__ hist1, u32* __restrict__ cnt) {
    __shared__ u32 cs[1024];
    int t = threadIdx.x;
    u32 s = 0;
    for (int b = t * 64; b < t * 64 + 64; b++) s += hist1[b];
    cs[t] = s;
    __syncthreads();
    if (t == 0) {
        u32 acc = 0; int B = 0; bool found = false;
        for (int q = 1023; q >= 0 && !found; q--) {
            if (acc + cs[q] >= TOPK) {
                for (int b = q * 64 + 63; b >= q * 64; b--) {
                    u32 h = hist1[b];
                    if (acc + h >= TOPK) { B = b; found = true; break; }
                    acc += h;
                }
            } else acc += cs[q];
        }
        cnt[3] = (u32)B;
        cnt[4] = acc;       // count of keys strictly above bin B
    }
}

__global__ void k_hist2(const u32* __restrict__ candKey, const u32* __restrict__ cnt,
                        u32* __restrict__ hist2) {
    u32 n = cnt[0] < (u32)MAXCAND ? cnt[0] : (u32)MAXCAND;
    u32 B = cnt[3];
    u32 stride = gridDim.x * blockDim.x;
    for (u32 i = blockIdx.x * blockDim.x + threadIdx.x; i < n; i += stride) {
        u32 k = candKey[i];
        if ((k >> 16) == B) atomicAdd(&hist2[k & 0xFFFFu], 1u);
    }
}

__global__ void __launch_bounds__(1024) k_cut2(const u32* __restrict__ hist2, u32* __restrict__ cnt) {
    __shared__ u32 cs[1024];
    int t = threadIdx.x;
    u32 s = 0;
    for (int b = t * 64; b < t * 64 + 64; b++) s += hist2[b];
    cs[t] = s;
    __syncthreads();
    if (t == 0) {
        u32 acc = cnt[4]; int L = 0; bool found = false;
        for (int q = 1023; q >= 0 && !found; q--) {
            if (acc + cs[q] >= TOPK) {
                for (int b = q * 64 + 63; b >= q * 64; b--) {
                    u32 h = hist2[b];
                    if (acc + h >= TOPK) { L = b; found = true; break; }
                    acc += h;
                }
            } else acc += cs[q];
        }
        u32 B = cnt[3];
        cnt[5] = (B << 16) | (u32)L;  // exact cutoff key
        cnt[6] = TOPK - acc;          // how many to take from the ==cutoff set (smallest idx first)
    }
}

__global__ void k_collect(const u32* __restrict__ candKey, const u32* __restrict__ candIdx,
                          u32* __restrict__ cnt, u64* __restrict__ sel, u32* __restrict__ eqI) {
    u32 n = cnt[0] < (u32)MAXCAND ? cnt[0] : (u32)MAXCAND;
    u32 cut = cnt[5];
    u32 stride = gridDim.x * blockDim.x;
    for (u32 i = blockIdx.x * blockDim.x + threadIdx.x; i < n; i += stride) {
        u32 k = candKey[i];
        if (k > cut) {
            u32 p = atomicAdd(&cnt[1], 1u);
            if (p < TOPK) sel[p] = ((u64)k << 32) | (u64)(0xFFFFFFFFu - candIdx[i]);
        } else if (k == cut) {
            u32 e = atomicAdd(&cnt[2], 1u);
            if (e < EQCAP) eqI[e] = candIdx[i];
        }
    }
}

__global__ void k_eq(const u32* __restrict__ eqI, u32* __restrict__ cnt, u64* __restrict__ sel) {
    u32 m = cnt[2] < (u32)EQCAP ? cnt[2] : (u32)EQCAP;
    u32 need = cnt[6];
    u32 base = cnt[1];
    u32 cut = cnt[5];
    for (u32 j = threadIdx.x; j < m; j += blockDim.x) {
        u32 v = eqI[j];
        u32 rank = 0;
        for (u32 k = 0; k < m; k++) rank += (eqI[k] < v) ? 1u : 0u;  // indices unique
        if (rank < need && base + rank < TOPK)
            sel[base + rank] = ((u64)cut << 32) | (u64)(0xFFFFFFFFu - v);
    }
}

// bitonic sort 4096 u64 keys descending (val desc, idx asc) + emit ranked data
__global__ void __launch_bounds__(1024) k_sort(u64* __restrict__ sel, const float* __restrict__ boxes,
                                               float* __restrict__ rboxes, float* __restrict__ rvals,
                                               int* __restrict__ rlabel, float* __restrict__ out) {
    __shared__ u64 lds[TOPK];
    int t = threadIdx.x;
    for (int i = t; i < TOPK; i += 1024) lds[i] = sel[i];
    __syncthreads();
    for (u32 k = 2; k <= TOPK; k <<= 1) {
        for (u32 j = k >> 1; j > 0; j >>= 1) {
            for (u32 q = t; q < TOPK / 2; q += 1024) {
                u32 i = ((q & ~(j - 1)) << 1) | (q & (j - 1));
                u32 p = i | j;
                u64 a = lds[i], b = lds[p];
                bool up = ((i & k) == 0);
                bool sw = up ? (a < b) : (a > b);   // descending overall
                if (sw) { lds[i] = b; lds[p] = a; }
            }
            __syncthreads();
        }
    }
    for (int r = t; r < TOPK; r += 1024) {
        u64 key = lds[r];
        if (key == 0ull) {  // impossible-underfill guard
            rboxes[r * 4 + 0] = 0; rboxes[r * 4 + 1] = 0; rboxes[r * 4 + 2] = 0; rboxes[r * 4 + 3] = 0;
            rvals[r] = 0.0f; rlabel[r] = 0;
            out[TOPK * 5 + r] = 0.0f;            // label
            out[TOPK * 6 + r] = 0.0f;            // keep
            float* d = out + (size_t)r * 5;
            d[0] = 0; d[1] = 0; d[2] = 0; d[3] = 0; d[4] = 0;
            continue;
        }
        u32 idx = 0xFFFFFFFFu - (u32)(key & 0xFFFFFFFFull);
        float val = __uint_as_float((u32)(key >> 32));
        u32 bi = idx / NCLS;
        u32 lab = idx % NCLS;
        const float* bp = boxes + (size_t)bi * 4;
        float x1 = fminf(fmaxf(bp[0], 0.0f), IMGW_M1);
        float y1 = fminf(fmaxf(bp[1], 0.0f), IMGH_M1);
        float x2 = fminf(fmaxf(bp[2], 0.0f), IMGW_M1);
        float y2 = fminf(fmaxf(bp[3], 0.0f), IMGH_M1);
        rboxes[r * 4 + 0] = x1; rboxes[r * 4 + 1] = y1;
        rboxes[r * 4 + 2] = x2; rboxes[r * 4 + 3] = y2;
        rvals[r] = val;
        rlabel[r] = (int)lab;
        out[TOPK * 5 + r] = (float)lab;          // labels output (unmasked in reference)
    }
}

// per-class greedy NMS: suppression is exactly class-local because the reference's
// label*4096 offset separates classes by >= 4096-1333 while clipped boxes are <=1333 wide.
__global__ void __launch_bounds__(256) k_nms(const float* __restrict__ rboxes,
                                             const float* __restrict__ rvals,
                                             const int* __restrict__ rlabel,
                                             float* __restrict__ out) {
    int c = blockIdx.x + 1;                     // labels are 1..80 (class 0 filtered)
    __shared__ unsigned short mem[TOPK];
    __shared__ unsigned char keepL[TOPK];
    __shared__ u32 ps[256];
    __shared__ u32 mtot;
    int t = threadIdx.x;
    int r0 = t * 16;
    u32 cl = 0;
    for (int r = r0; r < r0 + 16; r++) cl += (rlabel[r] == c) ? 1u : 0u;
    ps[t] = cl;
    __syncthreads();
    if (t == 0) {
        u32 acc = 0;
        for (int q = 0; q < 256; q++) { u32 v = ps[q]; ps[q] = acc; acc += v; }
        mtot = acc;
    }
    __syncthreads();
    u32 base = ps[t];
    for (int r = r0; r < r0 + 16; r++)
        if (rlabel[r] == c) mem[base++] = (unsigned short)r;  // stable: rank-ascending
    u32 m = mtot;
    for (u32 q = t; q < m; q += 256) keepL[q] = 1;
    __syncthreads();

    float off = (float)c * 4096.0f;             // replicate reference's f32 offset rounding
    for (u32 i = 0; i < m; i++) {
        __syncthreads();
        if (!keepL[i]) continue;                // uniform branch
        int ri = mem[i];
        float ix1 = rboxes[ri * 4 + 0] + off, iy1 = rboxes[ri * 4 + 1] + off;
        float ix2 = rboxes[ri * 4 + 2] + off, iy2 = rboxes[ri * 4 + 3] + off;
        float iarea = (ix2 - ix1) * (iy2 - iy1);
        for (u32 jj = i + 1 + t; jj < m; jj += 256) {
            if (!keepL[jj]) continue;
            int rj = mem[jj];
            float jx1 = rboxes[rj * 4 + 0] + off, jy1 = rboxes[rj * 4 + 1] + off;
            float jx2 = rboxes[rj * 4 + 2] + off, jy2 = rboxes[rj * 4 + 3] + off;
            float iw = fmaxf(fminf(ix2, jx2) - fmaxf(ix1, jx1), 0.0f);
            float ih = fmaxf(fminf(iy2, jy2) - fmaxf(iy1, jy1), 0.0f);
            float inter = iw * ih;
            float jarea = (jx2 - jx1) * (jy2 - jy1);
            float iou = inter / (iarea + jarea - inter + 1e-9f);
            if (iou > 0.5f) keepL[jj] = 0;
        }
    }
    __syncthreads();
    for (u32 q = t; q < m; q += 256) {
        int r = mem[q];
        int k = keepL[q];
        out[TOPK * 6 + r] = k ? 1.0f : 0.0f;    // keep output
        float* d = out + (size_t)r * 5;
        if (k) {
            d[0] = rboxes[r * 4 + 0]; d[1] = rboxes[r * 4 + 1];
            d[2] = rboxes[r * 4 + 2]; d[3] = rboxes[r * 4 + 3];
            d[4] = rvals[r];
        } else {
            d[0] = 0; d[1] = 0; d[2] = 0; d[3] = 0; d[4] = 0;
        }
    }
}

extern "C" void kernel_launch(void* const* d_in, const int* in_sizes, int n_in,
                              void* d_out, int out_size, void* d_ws, size_t ws_size,
                              hipStream_t stream) {
    const float* x = (const float*)d_in[0];
    const float* boxes = (const float*)d_in[1];
    float* out = (float*)d_out;

    u32* W = (u32*)d_ws;
    u32* cnt = W;                                 // 16
    u32* hist1 = W + 16;                          // 65536
    u32* hist2 = W + 16 + 65536;                  // 65536
    u64* sel = (u64*)(W + 16 + 2 * 65536);        // 4096 u64 (byte off 524352, 8B aligned)
    u32* candKey = W + 16 + 2 * 65536 + 2 * TOPK; // MAXCAND
    u32* candIdx = candKey + MAXCAND;
    u32* eqI = candIdx + MAXCAND;
    float* rboxes = (float*)(eqI + EQCAP);
    float* rvals = rboxes + 4 * TOPK;
    int* rlabel = (int*)(rvals + TOPK);

    const int nzero = 16 + 2 * 65536 + 2 * TOPK;  // cnt + hist1 + hist2 + sel (contiguous)
    k_zero<<<(nzero + 255) / 256, 256, 0, stream>>>(W, nzero);
    k_cand<<<(N_ROWS + 255) / 256, 256, 0, stream>>>(x, candKey, candIdx, cnt, hist1);
    k_cut1<<<1, 1024, 0, stream>>>(hist1, cnt);
    k_hist2<<<256, 256, 0, stream>>>(candKey, cnt, hist2);
    k_cut2<<<1, 1024, 0, stream>>>(hist2, cnt);
    k_collect<<<256, 256, 0, stream>>>(candKey, candIdx, cnt, sel, eqI);
    k_eq<<<1, 256, 0, stream>>>(eqI, cnt, sel);
    k_sort<<<1, 1024, 0, stream>>>(sel, boxes, rboxes, rvals, rlabel, out);
    k_nms<<<80, 256, 0, stream>>>(rboxes, rvals, rlabel, out);
}

// Round 3
// 355.423 us; speedup vs baseline: 1.9089x; 1.9089x over previous
//
#include <hip/hip_runtime.h>

#pragma clang fp contract(off)

typedef unsigned int u32;
typedef unsigned long long u64;

#define N_ROWS 32768
#define NCLS 81
#define TOPK 4096
#define MAXCAND 327680
#define EQCAP 8192
#define IMGW_M1 1332.0f
#define IMGH_M1 799.0f

// k_cand geometry: 1 wave per row, 8 rows per wave, 4 waves per block
#define ROWS_PER_WAVE 8
#define WAVES_PER_BLOCK 4
#define ROWS_PER_BLOCK (ROWS_PER_WAVE * WAVES_PER_BLOCK)   // 32
#define CAND_GRID (N_ROWS / ROWS_PER_BLOCK)                // 1024
// per-row candidate count is mathematically <= 19 (20 probs > 0.05 would sum > 1)
#define WAVE_CAND_CAP 160                                  // 8 rows * 19 = 152, rounded

// ---------------- ws layout (u32 units) ----------------
// [0,16)                     cnt: 0=candCount 1=selCount 2=eqCount 3=hiBin 4=countAboveHi 5=cutKey 6=numFromEqual
// [16, 16+65536)             hist1
// [+65536)                   hist2
// [131088, +8192)            sel (u64[4096])
// [139280, +MAXCAND)         candKey
// [+MAXCAND)                 candIdx
// [+EQCAP)                   eqIdx
// [+16384)                   rboxes (f32 4096x4)
// [+4096)                    rvals
// [+4096)                    rlabel (i32)

__global__ void k_zero(u32* __restrict__ p, int n) {
    int i = blockIdx.x * blockDim.x + threadIdx.x;
    if (i < n) p[i] = 0u;
}

// softmax: one wave per row, lane handles classes {lane, lane+64}.
// f64 accumulate (error ~1e-16 << ref's f32 error => our ordering == true ordering).
// Candidates compacted per-wave via ballot into LDS; ONE global atomic per block.
__global__ void __launch_bounds__(256) k_cand(const float* __restrict__ x,
                                              u32* __restrict__ candKey,
                                              u32* __restrict__ candIdx,
                                              u32* __restrict__ cnt,
                                              u32* __restrict__ hist1) {
    __shared__ u32 ldsK[WAVES_PER_BLOCK * WAVE_CAND_CAP];
    __shared__ u32 ldsI[WAVES_PER_BLOCK * WAVE_CAND_CAP];
    __shared__ u32 wcnt[WAVES_PER_BLOCK];
    __shared__ u32 wpre[WAVES_PER_BLOCK];
    __shared__ u32 gbaseSh;

    const int lane = threadIdx.x & 63;
    const int wave = threadIdx.x >> 6;
    const u32 wbase = (u32)wave * WAVE_CAND_CAP;
    const u64 laneLT = ((u64)1 << lane) - 1;

    u32 wloc = 0;  // wave-uniform running candidate count

    const int row0 = blockIdx.x * ROWS_PER_BLOCK + wave * ROWS_PER_WAVE;
    for (int rr = 0; rr < ROWS_PER_WAVE; rr++) {
        const int row = row0 + rr;
        const float* xr = x + (size_t)row * NCLS;
        const bool has2 = (lane < NCLS - 64);          // lanes 0..16
        float v0 = xr[lane];
        float v1 = has2 ? xr[lane + 64] : -3.0e38f;

        // wave max (exact, matches fmax over all 81)
        float m = fmaxf(v0, v1);
        #pragma unroll
        for (int d = 1; d < 64; d <<= 1) m = fmaxf(m, __shfl_xor(m, d));

        // f64 exp of f32-subtracted logits (same decision arithmetic as passing R2 kernel)
        float d0 = v0 - m;
        double e0 = exp((double)d0);
        double e1 = 0.0;
        if (has2) {
            float d1 = v1 - m;
            e1 = exp((double)d1);
        }
        double s = e0 + e1;
        #pragma unroll
        for (int d = 1; d < 64; d <<= 1) s += __shfl_xor(s, d);

        float pf0 = (float)(e0 / s);
        float pf1 = (float)(e1 / s);
        bool hasA = (lane >= 1) && (pf0 > 0.05f);       // class 0 excluded
        bool hasB = has2 && (pf1 > 0.05f);              // classes 64..80 all >= 1

        u64 maskA = __ballot(hasA);
        u64 maskB = __ballot(hasB);
        u32 totA = (u32)__popcll(maskA);
        u32 totB = (u32)__popcll(maskB);
        if (hasA) {
            u32 rk = wloc + (u32)__popcll(maskA & laneLT);
            ldsK[wbase + rk] = __float_as_uint(pf0);
            ldsI[wbase + rk] = (u32)(row * NCLS + lane);
        }
        if (hasB) {
            u32 rk = wloc + totA + (u32)__popcll(maskB & laneLT);
            ldsK[wbase + rk] = __float_as_uint(pf1);
            ldsI[wbase + rk] = (u32)(row * NCLS + lane + 64);
        }
        wloc += totA + totB;
    }

    if (lane == 0) wcnt[wave] = wloc;
    __syncthreads();
    if (threadIdx.x == 0) {
        u32 acc = 0;
        for (int w = 0; w < WAVES_PER_BLOCK; w++) { wpre[w] = acc; acc += wcnt[w]; }
        gbaseSh = (acc > 0) ? atomicAdd(&cnt[0], acc) : 0u;
    }
    __syncthreads();
    const u32 gbase = gbaseSh + wpre[wave];
    for (u32 i = lane; i < wloc; i += 64) {
        u32 g = gbase + i;
        if (g < MAXCAND) {
            u32 key = ldsK[wbase + i];
            candKey[g] = key;
            candIdx[g] = ldsI[wbase + i];
            atomicAdd(&hist1[key >> 16], 1u);   // scattered across ~560 bins
        }
    }
}

__global__ void __launch_bounds__(1024) k_cut1(const u32* __restrict__ hist1, u32* __restrict__ cnt) {
    __shared__ u32 cs[1024];
    int t = threadIdx.x;
    u32 s = 0;
    for (int b = t * 64; b < t * 64 + 64; b++) s += hist1[b];
    cs[t] = s;
    __syncthreads();
    if (t == 0) {
        u32 acc = 0; int B = 0; bool found = false;
        for (int q = 1023; q >= 0 && !found; q--) {
            if (acc + cs[q] >= TOPK) {
                for (int b = q * 64 + 63; b >= q * 64; b--) {
                    u32 h = hist1[b];
                    if (acc + h >= TOPK) { B = b; found = true; break; }
                    acc += h;
                }
            } else acc += cs[q];
        }
        cnt[3] = (u32)B;
        cnt[4] = acc;       // count of keys strictly above bin B
    }
}

__global__ void k_hist2(const u32* __restrict__ candKey, const u32* __restrict__ cnt,
                        u32* __restrict__ hist2) {
    u32 n = cnt[0] < (u32)MAXCAND ? cnt[0] : (u32)MAXCAND;
    u32 B = cnt[3];
    u32 stride = gridDim.x * blockDim.x;
    for (u32 i = blockIdx.x * blockDim.x + threadIdx.x; i < n; i += stride) {
        u32 k = candKey[i];
        if ((k >> 16) == B) atomicAdd(&hist2[k & 0xFFFFu], 1u);
    }
}

__global__ void __launch_bounds__(1024) k_cut2(const u32* __restrict__ hist2, u32* __restrict__ cnt) {
    __shared__ u32 cs[1024];
    int t = threadIdx.x;
    u32 s = 0;
    for (int b = t * 64; b < t * 64 + 64; b++) s += hist2[b];
    cs[t] = s;
    __syncthreads();
    if (t == 0) {
        u32 acc = cnt[4]; int L = 0; bool found = false;
        for (int q = 1023; q >= 0 && !found; q--) {
            if (acc + cs[q] >= TOPK) {
                for (int b = q * 64 + 63; b >= q * 64; b--) {
                    u32 h = hist2[b];
                    if (acc + h >= TOPK) { L = b; found = true; break; }
                    acc += h;
                }
            } else acc += cs[q];
        }
        u32 B = cnt[3];
        cnt[5] = (B << 16) | (u32)L;  // exact cutoff key
        cnt[6] = TOPK - acc;          // how many to take from the ==cutoff set (smallest idx first)
    }
}

__global__ void k_collect(const u32* __restrict__ candKey, const u32* __restrict__ candIdx,
                          u32* __restrict__ cnt, u64* __restrict__ sel, u32* __restrict__ eqI) {
    u32 n = cnt[0] < (u32)MAXCAND ? cnt[0] : (u32)MAXCAND;
    u32 cut = cnt[5];
    u32 stride = gridDim.x * blockDim.x;
    for (u32 i = blockIdx.x * blockDim.x + threadIdx.x; i < n; i += stride) {
        u32 k = candKey[i];
        if (k > cut) {
            u32 p = atomicAdd(&cnt[1], 1u);
            if (p < TOPK) sel[p] = ((u64)k << 32) | (u64)(0xFFFFFFFFu - candIdx[i]);
        } else if (k == cut) {
            u32 e = atomicAdd(&cnt[2], 1u);
            if (e < EQCAP) eqI[e] = candIdx[i];
        }
    }
}

__global__ void k_eq(const u32* __restrict__ eqI, u32* __restrict__ cnt, u64* __restrict__ sel) {
    u32 m = cnt[2] < (u32)EQCAP ? cnt[2] : (u32)EQCAP;
    u32 need = cnt[6];
    u32 base = cnt[1];
    u32 cut = cnt[5];
    for (u32 j = threadIdx.x; j < m; j += blockDim.x) {
        u32 v = eqI[j];
        u32 rank = 0;
        for (u32 k = 0; k < m; k++) rank += (eqI[k] < v) ? 1u : 0u;  // indices unique
        if (rank < need && base + rank < TOPK)
            sel[base + rank] = ((u64)cut << 32) | (u64)(0xFFFFFFFFu - v);
    }
}

// bitonic sort 4096 u64 keys descending (val desc, idx asc) + emit ranked data
__global__ void __launch_bounds__(1024) k_sort(u64* __restrict__ sel, const float* __restrict__ boxes,
                                               float* __restrict__ rboxes, float* __restrict__ rvals,
                                               int* __restrict__ rlabel, float* __restrict__ out) {
    __shared__ u64 lds[TOPK];
    int t = threadIdx.x;
    for (int i = t; i < TOPK; i += 1024) lds[i] = sel[i];
    __syncthreads();
    for (u32 k = 2; k <= TOPK; k <<= 1) {
        for (u32 j = k >> 1; j > 0; j >>= 1) {
            for (u32 q = t; q < TOPK / 2; q += 1024) {
                u32 i = ((q & ~(j - 1)) << 1) | (q & (j - 1));
                u32 p = i | j;
                u64 a = lds[i], b = lds[p];
                bool up = ((i & k) == 0);
                bool sw = up ? (a < b) : (a > b);   // descending overall
                if (sw) { lds[i] = b; lds[p] = a; }
            }
            __syncthreads();
        }
    }
    for (int r = t; r < TOPK; r += 1024) {
        u64 key = lds[r];
        if (key == 0ull) {  // impossible-underfill guard
            rboxes[r * 4 + 0] = 0; rboxes[r * 4 + 1] = 0; rboxes[r * 4 + 2] = 0; rboxes[r * 4 + 3] = 0;
            rvals[r] = 0.0f; rlabel[r] = 0;
            out[TOPK * 5 + r] = 0.0f;            // label
            out[TOPK * 6 + r] = 0.0f;            // keep
            float* d = out + (size_t)r * 5;
            d[0] = 0; d[1] = 0; d[2] = 0; d[3] = 0; d[4] = 0;
            continue;
        }
        u32 idx = 0xFFFFFFFFu - (u32)(key & 0xFFFFFFFFull);
        float val = __uint_as_float((u32)(key >> 32));
        u32 bi = idx / NCLS;
        u32 lab = idx % NCLS;
        const float* bp = boxes + (size_t)bi * 4;
        float x1 = fminf(fmaxf(bp[0], 0.0f), IMGW_M1);
        float y1 = fminf(fmaxf(bp[1], 0.0f), IMGH_M1);
        float x2 = fminf(fmaxf(bp[2], 0.0f), IMGW_M1);
        float y2 = fminf(fmaxf(bp[3], 0.0f), IMGH_M1);
        rboxes[r * 4 + 0] = x1; rboxes[r * 4 + 1] = y1;
        rboxes[r * 4 + 2] = x2; rboxes[r * 4 + 3] = y2;
        rvals[r] = val;
        rlabel[r] = (int)lab;
        out[TOPK * 5 + r] = (float)lab;          // labels output (unmasked in reference)
    }
}

// per-class greedy NMS: suppression is exactly class-local because the reference's
// label*4096 offset separates classes by >= 4096-1333 while clipped boxes are <=1333 wide.
__global__ void __launch_bounds__(256) k_nms(const float* __restrict__ rboxes,
                                             const float* __restrict__ rvals,
                                             const int* __restrict__ rlabel,
                                             float* __restrict__ out) {
    int c = blockIdx.x + 1;                     // labels are 1..80 (class 0 filtered)
    __shared__ unsigned short mem[TOPK];
    __shared__ unsigned char keepL[TOPK];
    __shared__ u32 ps[256];
    __shared__ u32 mtot;
    int t = threadIdx.x;
    int r0 = t * 16;
    u32 cl = 0;
    for (int r = r0; r < r0 + 16; r++) cl += (rlabel[r] == c) ? 1u : 0u;
    ps[t] = cl;
    __syncthreads();
    if (t == 0) {
        u32 acc = 0;
        for (int q = 0; q < 256; q++) { u32 v = ps[q]; ps[q] = acc; acc += v; }
        mtot = acc;
    }
    __syncthreads();
    u32 base = ps[t];
    for (int r = r0; r < r0 + 16; r++)
        if (rlabel[r] == c) mem[base++] = (unsigned short)r;  // stable: rank-ascending
    u32 m = mtot;
    for (u32 q = t; q < m; q += 256) keepL[q] = 1;
    __syncthreads();

    float off = (float)c * 4096.0f;             // replicate reference's f32 offset rounding
    for (u32 i = 0; i < m; i++) {
        __syncthreads();
        if (!keepL[i]) continue;                // uniform branch
        int ri = mem[i];
        float ix1 = rboxes[ri * 4 + 0] + off, iy1 = rboxes[ri * 4 + 1] + off;
        float ix2 = rboxes[ri * 4 + 2] + off, iy2 = rboxes[ri * 4 + 3] + off;
        float iarea = (ix2 - ix1) * (iy2 - iy1);
        for (u32 jj = i + 1 + t; jj < m; jj += 256) {
            if (!keepL[jj]) continue;
            int rj = mem[jj];
            float jx1 = rboxes[rj * 4 + 0] + off, jy1 = rboxes[rj * 4 + 1] + off;
            float jx2 = rboxes[rj * 4 + 2] + off, jy2 = rboxes[rj * 4 + 3] + off;
            float iw = fmaxf(fminf(ix2, jx2) - fmaxf(ix1, jx1), 0.0f);
            float ih = fmaxf(fminf(iy2, jy2) - fmaxf(iy1, jy1), 0.0f);
            float inter = iw * ih;
            float jarea = (jx2 - jx1) * (jy2 - jy1);
            float iou = inter / (iarea + jarea - inter + 1e-9f);
            if (iou > 0.5f) keepL[jj] = 0;
        }
    }
    __syncthreads();
    for (u32 q = t; q < m; q += 256) {
        int r = mem[q];
        int k = keepL[q];
        out[TOPK * 6 + r] = k ? 1.0f : 0.0f;    // keep output
        float* d = out + (size_t)r * 5;
        if (k) {
            d[0] = rboxes[r * 4 + 0]; d[1] = rboxes[r * 4 + 1];
            d[2] = rboxes[r * 4 + 2]; d[3] = rboxes[r * 4 + 3];
            d[4] = rvals[r];
        } else {
            d[0] = 0; d[1] = 0; d[2] = 0; d[3] = 0; d[4] = 0;
        }
    }
}

extern "C" void kernel_launch(void* const* d_in, const int* in_sizes, int n_in,
                              void* d_out, int out_size, void* d_ws, size_t ws_size,
                              hipStream_t stream) {
    const float* x = (const float*)d_in[0];
    const float* boxes = (const float*)d_in[1];
    float* out = (float*)d_out;

    u32* W = (u32*)d_ws;
    u32* cnt = W;                                 // 16
    u32* hist1 = W + 16;                          // 65536
    u32* hist2 = W + 16 + 65536;                  // 65536
    u64* sel = (u64*)(W + 16 + 2 * 65536);        // 4096 u64 (byte off 524352, 8B aligned)
    u32* candKey = W + 16 + 2 * 65536 + 2 * TOPK; // MAXCAND
    u32* candIdx = candKey + MAXCAND;
    u32* eqI = candIdx + MAXCAND;
    float* rboxes = (float*)(eqI + EQCAP);
    float* rvals = rboxes + 4 * TOPK;
    int* rlabel = (int*)(rvals + TOPK);

    const int nzero = 16 + 2 * 65536 + 2 * TOPK;  // cnt + hist1 + hist2 + sel (contiguous)
    k_zero<<<(nzero + 255) / 256, 256, 0, stream>>>(W, nzero);
    k_cand<<<CAND_GRID, 256, 0, stream>>>(x, candKey, candIdx, cnt, hist1);
    k_cut1<<<1, 1024, 0, stream>>>(hist1, cnt);
    k_hist2<<<256, 256, 0, stream>>>(candKey, cnt, hist2);
    k_cut2<<<1, 1024, 0, stream>>>(hist2, cnt);
    k_collect<<<256, 256, 0, stream>>>(candKey, candIdx, cnt, sel, eqI);
    k_eq<<<1, 256, 0, stream>>>(eqI, cnt, sel);
    k_sort<<<1, 1024, 0, stream>>>(sel, boxes, rboxes, rvals, rlabel, out);
    k_nms<<<80, 256, 0, stream>>>(rboxes, rvals, rlabel, out);
}

// Round 4
// 252.485 us; speedup vs baseline: 2.6872x; 1.4077x over previous
//
#include <hip/hip_runtime.h>

#pragma clang fp contract(off)

typedef unsigned int u32;
typedef unsigned long long u64;
typedef long long i64;

#define N_ROWS 32768
#define NCLS 81
#define TOPK 4096
#define MAXCAND 327680
#define EQCAP 8192
#define IMGW_M1 1332.0f
#define IMGH_M1 799.0f

// k_cand geometry: 4 threads per row (21+21+21+18 classes), 64 rows/block
#define QPR 4
#define CAND_THREADS 256
#define RPB (CAND_THREADS / QPR)          // 64 rows per block
#define CAND_GRID (N_ROWS / RPB)          // 512 blocks = 2048 waves = 2/SIMD
#define CPT 21                            // classes per thread (padded)
#define BLK_CAND_CAP 1280                 // 64 rows * <=19 cand/row = 1216 max

// ---------------- ws layout (u32 units) ----------------
// [0,16)                     cnt: 0=candCount 1=selCount 2=eqCount 3=hiBin 4=countAboveHi 5=cutKey 6=numFromEqual
// [16, +65536)               hist1
// [+65536)                   hist2
// [131088, +8192)            sel (u64[4096])
// [139280, +MAXCAND)         candKey
// [+MAXCAND)                 candIdx
// [+EQCAP)                   eqIdx
// [+16384)                   rboxes (f32 4096x4)
// [+4096)                    rvals
// [+4096)                    rlabel (i32)

__global__ void k_zero(u32* __restrict__ p, int n) {
    int i = blockIdx.x * blockDim.x + threadIdx.x;
    if (i < n) p[i] = 0u;
}

// fast f64 exp for d <= 0 (clamped at -45: dropped terms < 3e-20 never matter
// vs sum >= 1). Cody-Waite reduction (exact n*ln2_hi for |n|<2^20) + Taylor-13.
// Relative error ~3e-16 — decisions have >= f32-ulp (6e-8) margins.
__device__ inline double fast_exp_neg(double d) {
    if (d < -45.0) return 0.0;
    const double L2E    = 1.4426950408889634074;
    const double LN2_HI = 6.93147180369123816490e-01;  // 20 trailing zero bits
    const double LN2_LO = 1.90821492927058770002e-10;
    double n = __builtin_rint(d * L2E);                // n in [-65, 0]
    double r = __builtin_fma(-n, LN2_HI, d);
    r = __builtin_fma(-n, LN2_LO, r);
    double p = 1.0 / 6227020800.0;                     // 1/13!
    p = __builtin_fma(p, r, 1.0 / 479001600.0);
    p = __builtin_fma(p, r, 1.0 / 39916800.0);
    p = __builtin_fma(p, r, 1.0 / 3628800.0);
    p = __builtin_fma(p, r, 1.0 / 362880.0);
    p = __builtin_fma(p, r, 1.0 / 40320.0);
    p = __builtin_fma(p, r, 1.0 / 5040.0);
    p = __builtin_fma(p, r, 1.0 / 720.0);
    p = __builtin_fma(p, r, 1.0 / 120.0);
    p = __builtin_fma(p, r, 1.0 / 24.0);
    p = __builtin_fma(p, r, 1.0 / 6.0);
    p = __builtin_fma(p, r, 0.5);
    p = __builtin_fma(p, r, 1.0);
    p = __builtin_fma(p, r, 1.0);
    i64 ni = (i64)n;                                   // 2^n, n>=-65 -> normal
    double sc = __longlong_as_double((i64)(1023 + ni) << 52);
    return p * sc;
}

// softmax + threshold + compaction: 4 threads/row, 21 independent exps/thread
// (ILP), 2-step xor reductions, division only for candidates.
__global__ void __launch_bounds__(256) k_cand(const float* __restrict__ x,
                                              u32* __restrict__ candKey,
                                              u32* __restrict__ candIdx,
                                              u32* __restrict__ cnt,
                                              u32* __restrict__ hist1) {
    __shared__ u32 lK[BLK_CAND_CAP];
    __shared__ u32 lI[BLK_CAND_CAP];
    __shared__ u32 lcnt;
    __shared__ u32 gbaseSh;
    const int t = threadIdx.x;
    if (t == 0) lcnt = 0;
    __syncthreads();

    const int row = blockIdx.x * RPB + (t >> 2);
    const int q = t & 3;
    const int c0 = q * CPT;                       // 0,21,42,63
    const float* xr = x + (size_t)row * NCLS;

    float v[CPT];
    #pragma unroll
    for (int i = 0; i < CPT; i++) {
        int c = c0 + i;
        v[i] = (c < NCLS) ? xr[c] : -1.0e30f;     // pad -> exp clamps to 0
    }
    float m = v[0];
    #pragma unroll
    for (int i = 1; i < CPT; i++) m = fmaxf(m, v[i]);
    m = fmaxf(m, __shfl_xor(m, 1));
    m = fmaxf(m, __shfl_xor(m, 2));               // row max (lanes 4k..4k+3)

    double e[CPT];
    double s = 0.0;
    #pragma unroll
    for (int i = 0; i < CPT; i++) {
        float d = v[i] - m;                       // f32 subtract, as reference
        e[i] = fast_exp_neg((double)d);
        s += e[i];
    }
    s += __shfl_xor(s, 1);
    s += __shfl_xor(s, 2);                        // butterfly: identical s in all 4 lanes

    // float(q)>0.05f  <=>  q > 0.05f + 2^-29 (half-ulp midpoint); test via f64 mul
    const double THRMID = (double)0.05f + 0x1.0p-29;
    double ethr = THRMID * s;
    #pragma unroll
    for (int i = 0; i < CPT; i++) {
        int c = c0 + i;
        if (c != 0 && c < NCLS && e[i] > ethr) {
            float pf = (float)(e[i] / s);         // exact f64 division, rare
            u32 slot = atomicAdd(&lcnt, 1u);
            lK[slot] = __float_as_uint(pf);
            lI[slot] = (u32)(row * NCLS + c);
        }
    }
    __syncthreads();
    u32 tot = lcnt;
    if (t == 0) gbaseSh = tot ? atomicAdd(&cnt[0], tot) : 0u;
    __syncthreads();
    u32 gbase = gbaseSh;
    for (u32 i = t; i < tot; i += CAND_THREADS) {
        u32 g = gbase + i;
        if (g < MAXCAND) {
            u32 key = lK[i];
            candKey[g] = key;
            candIdx[g] = lI[i];
            atomicAdd(&hist1[key >> 16], 1u);
        }
    }
}

// parallel suffix-scan cutoff finder over 65536-bin histogram
__global__ void __launch_bounds__(1024) k_cut1(const u32* __restrict__ hist1, u32* __restrict__ cnt) {
    __shared__ u32 cs[1024];
    int t = threadIdx.x;
    u32 s = 0;
    const u32* hp = hist1 + t * 64;
    for (int b = 0; b < 64; b++) s += hp[b];
    cs[t] = s;
    __syncthreads();
    for (int d = 1; d < 1024; d <<= 1) {          // inclusive suffix sum
        u32 v = (t + d < 1024) ? cs[t + d] : 0u;
        __syncthreads();
        cs[t] += v;
        __syncthreads();
    }
    u32 S_t = cs[t];
    u32 S_next = (t < 1023) ? cs[t + 1] : 0u;
    if (S_next < TOPK && S_t >= TOPK) {           // exactly one thread
        u32 acc = S_next;
        int B = t * 64;
        for (int b = t * 64 + 63; b >= t * 64; b--) {
            u32 h = hist1[b];
            if (acc + h >= TOPK) { B = b; break; }
            acc += h;
        }
        cnt[3] = (u32)B;
        cnt[4] = acc;                             // count strictly above bin B
    }
}

__global__ void k_hist2(const u32* __restrict__ candKey, const u32* __restrict__ cnt,
                        u32* __restrict__ hist2) {
    u32 n = cnt[0] < (u32)MAXCAND ? cnt[0] : (u32)MAXCAND;
    u32 B = cnt[3];
    u32 stride = gridDim.x * blockDim.x;
    for (u32 i = blockIdx.x * blockDim.x + threadIdx.x; i < n; i += stride) {
        u32 k = candKey[i];
        if ((k >> 16) == B) atomicAdd(&hist2[k & 0xFFFFu], 1u);
    }
}

__global__ void __launch_bounds__(1024) k_cut2(const u32* __restrict__ hist2, u32* __restrict__ cnt) {
    __shared__ u32 cs[1024];
    int t = threadIdx.x;
    u32 C = cnt[4];
    u32 s = 0;
    const u32* hp = hist2 + t * 64;
    for (int b = 0; b < 64; b++) s += hp[b];
    cs[t] = s;
    __syncthreads();
    for (int d = 1; d < 1024; d <<= 1) {
        u32 v = (t + d < 1024) ? cs[t + d] : 0u;
        __syncthreads();
        cs[t] += v;
        __syncthreads();
    }
    u32 S_t = cs[t];
    u32 S_next = (t < 1023) ? cs[t + 1] : 0u;
    if (C + S_next < TOPK && C + S_t >= TOPK) {
        u32 acc = C + S_next;
        int L = t * 64;
        for (int b = t * 64 + 63; b >= t * 64; b--) {
            u32 h = hist2[b];
            if (acc + h >= TOPK) { L = b; break; }
            acc += h;
        }
        cnt[5] = (cnt[3] << 16) | (u32)L;         // exact cutoff key
        cnt[6] = TOPK - acc;                      // take from ==cutoff set
    }
}

__global__ void k_collect(const u32* __restrict__ candKey, const u32* __restrict__ candIdx,
                          u32* __restrict__ cnt, u64* __restrict__ sel, u32* __restrict__ eqI) {
    u32 n = cnt[0] < (u32)MAXCAND ? cnt[0] : (u32)MAXCAND;
    u32 cut = cnt[5];
    u32 stride = gridDim.x * blockDim.x;
    for (u32 i = blockIdx.x * blockDim.x + threadIdx.x; i < n; i += stride) {
        u32 k = candKey[i];
        if (k > cut) {
            u32 p = atomicAdd(&cnt[1], 1u);
            if (p < TOPK) sel[p] = ((u64)k << 32) | (u64)(0xFFFFFFFFu - candIdx[i]);
        } else if (k == cut) {
            u32 e = atomicAdd(&cnt[2], 1u);
            if (e < EQCAP) eqI[e] = candIdx[i];
        }
    }
}

// eq-fill + bitonic sort 4096 u64 (val desc, idx asc) + gather/clip/emit
__global__ void __launch_bounds__(1024) k_sort(const u64* __restrict__ sel,
                                               const u32* __restrict__ eqI,
                                               const u32* __restrict__ cnt,
                                               const float* __restrict__ boxes,
                                               float* __restrict__ rboxes, float* __restrict__ rvals,
                                               int* __restrict__ rlabel, float* __restrict__ out) {
    __shared__ u64 lds[TOPK];
    int t = threadIdx.x;
    u32 nsel = cnt[1] < (u32)TOPK ? cnt[1] : (u32)TOPK;
    for (int i = t; i < TOPK; i += 1024) lds[i] = ((u32)i < nsel) ? sel[i] : 0ull;
    __syncthreads();
    {   // former k_eq: rank ==cutoff candidates by ascending index
        u32 mm = cnt[2] < (u32)EQCAP ? cnt[2] : (u32)EQCAP;
        u32 need = cnt[6];
        u32 base = cnt[1];
        u32 cut = cnt[5];
        for (u32 j = t; j < mm; j += 1024) {
            u32 v = eqI[j];
            u32 rank = 0;
            for (u32 k = 0; k < mm; k++) rank += (eqI[k] < v) ? 1u : 0u;  // unique
            if (rank < need && base + rank < TOPK)
                lds[base + rank] = ((u64)cut << 32) | (u64)(0xFFFFFFFFu - v);
        }
    }
    __syncthreads();
    for (u32 k = 2; k <= TOPK; k <<= 1) {
        for (u32 j = k >> 1; j > 0; j >>= 1) {
            for (u32 q = t; q < TOPK / 2; q += 1024) {
                u32 i = ((q & ~(j - 1)) << 1) | (q & (j - 1));
                u32 p = i | j;
                u64 a = lds[i], b = lds[p];
                bool up = ((i & k) == 0);
                bool sw = up ? (a < b) : (a > b);   // descending overall
                if (sw) { lds[i] = b; lds[p] = a; }
            }
            __syncthreads();
        }
    }
    for (int r = t; r < TOPK; r += 1024) {
        u64 key = lds[r];
        if (key == 0ull) {  // impossible-underfill guard
            rboxes[r * 4 + 0] = 0; rboxes[r * 4 + 1] = 0; rboxes[r * 4 + 2] = 0; rboxes[r * 4 + 3] = 0;
            rvals[r] = 0.0f; rlabel[r] = 0;
            out[TOPK * 5 + r] = 0.0f;
            out[TOPK * 6 + r] = 0.0f;
            float* d = out + (size_t)r * 5;
            d[0] = 0; d[1] = 0; d[2] = 0; d[3] = 0; d[4] = 0;
            continue;
        }
        u32 idx = 0xFFFFFFFFu - (u32)(key & 0xFFFFFFFFull);
        float val = __uint_as_float((u32)(key >> 32));
        u32 bi = idx / NCLS;
        u32 lab = idx % NCLS;
        const float* bp = boxes + (size_t)bi * 4;
        float x1 = fminf(fmaxf(bp[0], 0.0f), IMGW_M1);
        float y1 = fminf(fmaxf(bp[1], 0.0f), IMGH_M1);
        float x2 = fminf(fmaxf(bp[2], 0.0f), IMGW_M1);
        float y2 = fminf(fmaxf(bp[3], 0.0f), IMGH_M1);
        rboxes[r * 4 + 0] = x1; rboxes[r * 4 + 1] = y1;
        rboxes[r * 4 + 2] = x2; rboxes[r * 4 + 3] = y2;
        rvals[r] = val;
        rlabel[r] = (int)lab;
        out[TOPK * 5 + r] = (float)lab;          // labels (unmasked in reference)
    }
}

// per-class greedy NMS: suppression is exactly class-local because the reference's
// label*4096 offset separates classes by >= 4096-1333 while clipped boxes are <=1333 wide.
__global__ void __launch_bounds__(256) k_nms(const float* __restrict__ rboxes,
                                             const float* __restrict__ rvals,
                                             const int* __restrict__ rlabel,
                                             float* __restrict__ out) {
    int c = blockIdx.x + 1;                     // labels 1..80 (class 0 filtered)
    __shared__ unsigned short mem[TOPK];
    __shared__ unsigned char keepL[TOPK];
    __shared__ u32 ps[256];
    __shared__ u32 mtot;
    int t = threadIdx.x;
    int r0 = t * 16;
    u32 cl = 0;
    for (int r = r0; r < r0 + 16; r++) cl += (rlabel[r] == c) ? 1u : 0u;
    ps[t] = cl;
    __syncthreads();
    if (t == 0) {
        u32 acc = 0;
        for (int q = 0; q < 256; q++) { u32 v = ps[q]; ps[q] = acc; acc += v; }
        mtot = acc;
    }
    __syncthreads();
    u32 base = ps[t];
    for (int r = r0; r < r0 + 16; r++)
        if (rlabel[r] == c) mem[base++] = (unsigned short)r;  // stable: rank-ascending
    u32 m = mtot;
    for (u32 q = t; q < m; q += 256) keepL[q] = 1;
    __syncthreads();

    float off = (float)c * 4096.0f;             // replicate reference's f32 offset rounding
    for (u32 i = 0; i < m; i++) {
        __syncthreads();
        if (!keepL[i]) continue;                // uniform branch
        int ri = mem[i];
        float ix1 = rboxes[ri * 4 + 0] + off, iy1 = rboxes[ri * 4 + 1] + off;
        float ix2 = rboxes[ri * 4 + 2] + off, iy2 = rboxes[ri * 4 + 3] + off;
        float iarea = (ix2 - ix1) * (iy2 - iy1);
        for (u32 jj = i + 1 + t; jj < m; jj += 256) {
            if (!keepL[jj]) continue;
            int rj = mem[jj];
            float jx1 = rboxes[rj * 4 + 0] + off, jy1 = rboxes[rj * 4 + 1] + off;
            float jx2 = rboxes[rj * 4 + 2] + off, jy2 = rboxes[rj * 4 + 3] + off;
            float iw = fmaxf(fminf(ix2, jx2) - fmaxf(ix1, jx1), 0.0f);
            float ih = fmaxf(fminf(iy2, jy2) - fmaxf(iy1, jy1), 0.0f);
            float inter = iw * ih;
            float jarea = (jx2 - jx1) * (jy2 - jy1);
            float iou = inter / (iarea + jarea - inter + 1e-9f);
            if (iou > 0.5f) keepL[jj] = 0;
        }
    }
    __syncthreads();
    for (u32 q = t; q < m; q += 256) {
        int r = mem[q];
        int k = keepL[q];
        out[TOPK * 6 + r] = k ? 1.0f : 0.0f;
        float* d = out + (size_t)r * 5;
        if (k) {
            d[0] = rboxes[r * 4 + 0]; d[1] = rboxes[r * 4 + 1];
            d[2] = rboxes[r * 4 + 2]; d[3] = rboxes[r * 4 + 3];
            d[4] = rvals[r];
        } else {
            d[0] = 0; d[1] = 0; d[2] = 0; d[3] = 0; d[4] = 0;
        }
    }
}

extern "C" void kernel_launch(void* const* d_in, const int* in_sizes, int n_in,
                              void* d_out, int out_size, void* d_ws, size_t ws_size,
                              hipStream_t stream) {
    const float* x = (const float*)d_in[0];
    const float* boxes = (const float*)d_in[1];
    float* out = (float*)d_out;

    u32* W = (u32*)d_ws;
    u32* cnt = W;                                 // 16
    u32* hist1 = W + 16;                          // 65536
    u32* hist2 = W + 16 + 65536;                  // 65536
    u64* sel = (u64*)(W + 16 + 2 * 65536);        // 4096 u64 (8B aligned)
    u32* candKey = W + 16 + 2 * 65536 + 2 * TOPK; // MAXCAND
    u32* candIdx = candKey + MAXCAND;
    u32* eqI = candIdx + MAXCAND;
    float* rboxes = (float*)(eqI + EQCAP);
    float* rvals = rboxes + 4 * TOPK;
    int* rlabel = (int*)(rvals + TOPK);

    const int nzero = 16 + 2 * 65536;             // cnt + hist1 + hist2 (sel init'd in k_sort)
    k_zero<<<(nzero + 255) / 256, 256, 0, stream>>>(W, nzero);
    k_cand<<<CAND_GRID, CAND_THREADS, 0, stream>>>(x, candKey, candIdx, cnt, hist1);
    k_cut1<<<1, 1024, 0, stream>>>(hist1, cnt);
    k_hist2<<<256, 256, 0, stream>>>(candKey, cnt, hist2);
    k_cut2<<<1, 1024, 0, stream>>>(hist2, cnt);
    k_collect<<<256, 256, 0, stream>>>(candKey, candIdx, cnt, sel, eqI);
    k_sort<<<1, 1024, 0, stream>>>(sel, eqI, cnt, boxes, rboxes, rvals, rlabel, out);
    k_nms<<<80, 256, 0, stream>>>(rboxes, rvals, rlabel, out);
}

// Round 5
// 247.764 us; speedup vs baseline: 2.7384x; 1.0191x over previous
//
#include <hip/hip_runtime.h>

#pragma clang fp contract(off)

typedef unsigned int u32;
typedef unsigned long long u64;
typedef long long i64;

#define N_ROWS 32768
#define NCLS 81
#define TOPK 4096
#define MAXCAND 327680
#define EQCAP 8192
#define IMGW_M1 1332.0f
#define IMGH_M1 799.0f

// k_cand geometry: 8 threads/row, 32 rows/block, 1024 blocks (4 blocks/CU)
#define CAND_THREADS 256
#define RPB 32
#define CAND_GRID (N_ROWS / RPB)          // 1024
#define CPT 11                            // max classes/thread (thread 7: 11, others 10)
#define BLK_CAND_CAP 640                  // 32 rows * <=19 cand/row = 608 max
#define ROW_F4 ((RPB * NCLS) / 4)         // 648 float4 per block slice (exactly)

// k_collect geometry
#define COLL_GRID 512
#define COLL_CAP 640                      // MAXCAND / COLL_GRID

// ---------------- ws layout (u32 units) ----------------
// [0,16)                     cnt: 0=candCount 1=selCount 2=eqCount 3=hiBin 4=countAboveHi 5=cutKey 6=numFromEqual
// [16, +65536)               hist1
// [+65536)                   hist2
// [131088, +8192)            sel (u64[4096])
// [139280, +MAXCAND)         candKey
// [+MAXCAND)                 candIdx
// [+EQCAP)                   eqIdx
// [+16384)                   rboxes (f32 4096x4)
// [+4096)                    rvals
// [+4096)                    rlabel (i32)

__global__ void k_zero(u32* __restrict__ p, int n) {
    int i = blockIdx.x * blockDim.x + threadIdx.x;
    if (i < n) p[i] = 0u;
}

// fast f64 exp for d <= 0 (clamped at -45: dropped terms < 3e-20 never matter
// vs sum >= 1). Cody-Waite reduction (exact n*ln2_hi for |n|<2^20) + Taylor-13.
// Relative error ~3e-16 — decisions have >= f32-ulp (6e-8) margins.
__device__ inline double fast_exp_neg(double d) {
    if (d < -45.0) return 0.0;
    const double L2E    = 1.4426950408889634074;
    const double LN2_HI = 6.93147180369123816490e-01;  // 20 trailing zero bits
    const double LN2_LO = 1.90821492927058770002e-10;
    double n = __builtin_rint(d * L2E);                // n in [-65, 0]
    double r = __builtin_fma(-n, LN2_HI, d);
    r = __builtin_fma(-n, LN2_LO, r);
    double p = 1.0 / 6227020800.0;                     // 1/13!
    p = __builtin_fma(p, r, 1.0 / 479001600.0);
    p = __builtin_fma(p, r, 1.0 / 39916800.0);
    p = __builtin_fma(p, r, 1.0 / 3628800.0);
    p = __builtin_fma(p, r, 1.0 / 362880.0);
    p = __builtin_fma(p, r, 1.0 / 40320.0);
    p = __builtin_fma(p, r, 1.0 / 5040.0);
    p = __builtin_fma(p, r, 1.0 / 720.0);
    p = __builtin_fma(p, r, 1.0 / 120.0);
    p = __builtin_fma(p, r, 1.0 / 24.0);
    p = __builtin_fma(p, r, 1.0 / 6.0);
    p = __builtin_fma(p, r, 0.5);
    p = __builtin_fma(p, r, 1.0);
    p = __builtin_fma(p, r, 1.0);
    i64 ni = (i64)n;                                   // 2^n, n>=-65 -> normal
    double sc = __longlong_as_double((i64)(1023 + ni) << 52);
    return p * sc;
}

// softmax + threshold + compaction.
// Stage the block's 32-row slice (648 float4, exactly 16B-aligned since
// 32*81*4 = 10368 = 648*16) into LDS with coalesced loads, then 8 threads/row.
__global__ void __launch_bounds__(256, 4) k_cand(const float* __restrict__ x,
                                                 u32* __restrict__ candKey,
                                                 u32* __restrict__ candIdx,
                                                 u32* __restrict__ cnt,
                                                 u32* __restrict__ hist1) {
    __shared__ float4 lx4[ROW_F4];
    __shared__ u32 lK[BLK_CAND_CAP];
    __shared__ u32 lI[BLK_CAND_CAP];
    __shared__ u32 lcnt;
    __shared__ u32 gbaseSh;
    float* lx = (float*)lx4;
    const int t = threadIdx.x;
    if (t == 0) lcnt = 0;

    // coalesced global -> LDS staging
    const float4* xv = (const float4*)x + (size_t)blockIdx.x * ROW_F4;
    for (int i = t; i < ROW_F4; i += CAND_THREADS) lx4[i] = xv[i];
    __syncthreads();

    const int rl = t >> 3;                        // local row 0..31
    const int q = t & 7;
    const int c0 = q * 10;                        // thread 7 covers 70..80 (11 classes)
    const int cEff = (q == 7) ? 11 : 10;
    const int row = blockIdx.x * RPB + rl;
    const float* xr = lx + rl * NCLS;

    float v[CPT];
    #pragma unroll
    for (int i = 0; i < CPT; i++) v[i] = (i < cEff) ? xr[c0 + i] : -1.0e30f;

    float m = v[0];
    #pragma unroll
    for (int i = 1; i < CPT; i++) m = fmaxf(m, v[i]);
    m = fmaxf(m, __shfl_xor(m, 1));
    m = fmaxf(m, __shfl_xor(m, 2));
    m = fmaxf(m, __shfl_xor(m, 4));               // row max across 8-lane group

    double e[CPT];
    double s = 0.0;
    #pragma unroll
    for (int i = 0; i < CPT; i++) {
        if (i < cEff) {
            float d = v[i] - m;                   // f32 subtract, as reference
            e[i] = fast_exp_neg((double)d);
            s += e[i];
        } else e[i] = 0.0;
    }
    s += __shfl_xor(s, 1);
    s += __shfl_xor(s, 2);
    s += __shfl_xor(s, 4);                        // butterfly: identical s in group

    // float(p)>0.05f  <=>  p > 0.05f + 2^-29 (half-ulp midpoint); f64 mul, no div
    const double THRMID = (double)0.05f + 0x1.0p-29;
    double ethr = THRMID * s;
    #pragma unroll
    for (int i = 0; i < CPT; i++) {
        int c = c0 + i;
        if (i < cEff && c != 0 && e[i] > ethr) {
            float pf = (float)(e[i] / s);         // exact f64 division, rare
            u32 slot = atomicAdd(&lcnt, 1u);
            lK[slot] = __float_as_uint(pf);
            lI[slot] = (u32)(row * NCLS + c);
        }
    }
    __syncthreads();
    u32 tot = lcnt;
    if (t == 0) gbaseSh = tot ? atomicAdd(&cnt[0], tot) : 0u;
    __syncthreads();
    u32 gbase = gbaseSh;
    for (u32 i = t; i < tot; i += CAND_THREADS) {
        u32 g = gbase + i;
        if (g < MAXCAND) {
            u32 key = lK[i];
            candKey[g] = key;
            candIdx[g] = lI[i];
            atomicAdd(&hist1[key >> 16], 1u);     // scattered across ~560 bins
        }
    }
}

// parallel suffix-scan cutoff finder over 65536-bin histogram
__global__ void __launch_bounds__(1024) k_cut1(const u32* __restrict__ hist1, u32* __restrict__ cnt) {
    __shared__ u32 cs[1024];
    int t = threadIdx.x;
    u32 s = 0;
    const u32* hp = hist1 + t * 64;
    for (int b = 0; b < 64; b++) s += hp[b];
    cs[t] = s;
    __syncthreads();
    for (int d = 1; d < 1024; d <<= 1) {          // inclusive suffix sum
        u32 v = (t + d < 1024) ? cs[t + d] : 0u;
        __syncthreads();
        cs[t] += v;
        __syncthreads();
    }
    u32 S_t = cs[t];
    u32 S_next = (t < 1023) ? cs[t + 1] : 0u;
    if (S_next < TOPK && S_t >= TOPK) {           // exactly one thread
        u32 acc = S_next;
        int B = t * 64;
        for (int b = t * 64 + 63; b >= t * 64; b--) {
            u32 h = hist1[b];
            if (acc + h >= TOPK) { B = b; break; }
            acc += h;
        }
        cnt[3] = (u32)B;
        cnt[4] = acc;                             // count strictly above bin B
    }
}

__global__ void k_hist2(const u32* __restrict__ candKey, const u32* __restrict__ cnt,
                        u32* __restrict__ hist2) {
    u32 n = cnt[0] < (u32)MAXCAND ? cnt[0] : (u32)MAXCAND;
    u32 B = cnt[3];
    u32 stride = gridDim.x * blockDim.x;
    for (u32 i = blockIdx.x * blockDim.x + threadIdx.x; i < n; i += stride) {
        u32 k = candKey[i];
        if ((k >> 16) == B) atomicAdd(&hist2[k & 0xFFFFu], 1u);
    }
}

__global__ void __launch_bounds__(1024) k_cut2(const u32* __restrict__ hist2, u32* __restrict__ cnt) {
    __shared__ u32 cs[1024];
    int t = threadIdx.x;
    u32 C = cnt[4];
    u32 s = 0;
    const u32* hp = hist2 + t * 64;
    for (int b = 0; b < 64; b++) s += hp[b];
    cs[t] = s;
    __syncthreads();
    for (int d = 1; d < 1024; d <<= 1) {
        u32 v = (t + d < 1024) ? cs[t + d] : 0u;
        __syncthreads();
        cs[t] += v;
        __syncthreads();
    }
    u32 S_t = cs[t];
    u32 S_next = (t < 1023) ? cs[t + 1] : 0u;
    if (C + S_next < TOPK && C + S_t >= TOPK) {
        u32 acc = C + S_next;
        int L = t * 64;
        for (int b = t * 64 + 63; b >= t * 64; b--) {
            u32 h = hist2[b];
            if (acc + h >= TOPK) { L = b; break; }
            acc += h;
        }
        cnt[5] = (cnt[3] << 16) | (u32)L;         // exact cutoff key
        cnt[6] = TOPK - acc;                      // take from ==cutoff set
    }
}

// block-aggregated collect: LDS staging + ONE global atomic per block per list
__global__ void __launch_bounds__(256) k_collect(const u32* __restrict__ candKey,
                                                 const u32* __restrict__ candIdx,
                                                 u32* __restrict__ cnt,
                                                 u64* __restrict__ sel,
                                                 u32* __restrict__ eqI) {
    __shared__ u64 sStage[COLL_CAP];
    __shared__ u32 eStage[COLL_CAP];
    __shared__ u32 sc, ec, sb, eb;
    int t = threadIdx.x;
    if (t == 0) { sc = 0; ec = 0; }
    __syncthreads();
    u32 n = cnt[0] < (u32)MAXCAND ? cnt[0] : (u32)MAXCAND;
    u32 chunk = (n + COLL_GRID - 1) / COLL_GRID;  // <= 640 by construction
    u32 lo = blockIdx.x * chunk;
    u32 hi = lo + chunk; if (hi > n) hi = n;
    u32 cut = cnt[5];
    for (u32 i = lo + t; i < hi; i += 256) {
        u32 k = candKey[i];
        if (k > cut) {
            u32 p = atomicAdd(&sc, 1u);
            sStage[p] = ((u64)k << 32) | (u64)(0xFFFFFFFFu - candIdx[i]);
        } else if (k == cut) {
            u32 e2 = atomicAdd(&ec, 1u);
            eStage[e2] = candIdx[i];
        }
    }
    __syncthreads();
    if (t == 0) {
        sb = sc ? atomicAdd(&cnt[1], sc) : 0u;
        eb = ec ? atomicAdd(&cnt[2], ec) : 0u;
    }
    __syncthreads();
    for (u32 i = t; i < sc; i += 256) { u32 g = sb + i; if (g < TOPK) sel[g] = sStage[i]; }
    for (u32 i = t; i < ec; i += 256) { u32 g = eb + i; if (g < EQCAP) eqI[g] = eStage[i]; }
}

// eq-fill + bitonic sort 4096 u64 (val desc, idx asc) + gather/clip/emit
__global__ void __launch_bounds__(1024) k_sort(const u64* __restrict__ sel,
                                               const u32* __restrict__ eqI,
                                               const u32* __restrict__ cnt,
                                               const float* __restrict__ boxes,
                                               float* __restrict__ rboxes, float* __restrict__ rvals,
                                               int* __restrict__ rlabel, float* __restrict__ out) {
    __shared__ u64 lds[TOPK];
    int t = threadIdx.x;
    u32 nsel = cnt[1] < (u32)TOPK ? cnt[1] : (u32)TOPK;
    for (int i = t; i < TOPK; i += 1024) lds[i] = ((u32)i < nsel) ? sel[i] : 0ull;
    __syncthreads();
    {   // rank ==cutoff candidates by ascending index
        u32 mm = cnt[2] < (u32)EQCAP ? cnt[2] : (u32)EQCAP;
        u32 need = cnt[6];
        u32 base = cnt[1];
        u32 cut = cnt[5];
        for (u32 j = t; j < mm; j += 1024) {
            u32 v = eqI[j];
            u32 rank = 0;
            for (u32 k = 0; k < mm; k++) rank += (eqI[k] < v) ? 1u : 0u;  // unique
            if (rank < need && base + rank < TOPK)
                lds[base + rank] = ((u64)cut << 32) | (u64)(0xFFFFFFFFu - v);
        }
    }
    __syncthreads();
    for (u32 k = 2; k <= TOPK; k <<= 1) {
        for (u32 j = k >> 1; j > 0; j >>= 1) {
            for (u32 q = t; q < TOPK / 2; q += 1024) {
                u32 i = ((q & ~(j - 1)) << 1) | (q & (j - 1));
                u32 p = i | j;
                u64 a = lds[i], b = lds[p];
                bool up = ((i & k) == 0);
                bool sw = up ? (a < b) : (a > b);   // descending overall
                if (sw) { lds[i] = b; lds[p] = a; }
            }
            __syncthreads();
        }
    }
    for (int r = t; r < TOPK; r += 1024) {
        u64 key = lds[r];
        if (key == 0ull) {  // impossible-underfill guard
            rboxes[r * 4 + 0] = 0; rboxes[r * 4 + 1] = 0; rboxes[r * 4 + 2] = 0; rboxes[r * 4 + 3] = 0;
            rvals[r] = 0.0f; rlabel[r] = 0;
            out[TOPK * 5 + r] = 0.0f;
            out[TOPK * 6 + r] = 0.0f;
            float* d = out + (size_t)r * 5;
            d[0] = 0; d[1] = 0; d[2] = 0; d[3] = 0; d[4] = 0;
            continue;
        }
        u32 idx = 0xFFFFFFFFu - (u32)(key & 0xFFFFFFFFull);
        float val = __uint_as_float((u32)(key >> 32));
        u32 bi = idx / NCLS;
        u32 lab = idx % NCLS;
        const float* bp = boxes + (size_t)bi * 4;
        float x1 = fminf(fmaxf(bp[0], 0.0f), IMGW_M1);
        float y1 = fminf(fmaxf(bp[1], 0.0f), IMGH_M1);
        float x2 = fminf(fmaxf(bp[2], 0.0f), IMGW_M1);
        float y2 = fminf(fmaxf(bp[3], 0.0f), IMGH_M1);
        rboxes[r * 4 + 0] = x1; rboxes[r * 4 + 1] = y1;
        rboxes[r * 4 + 2] = x2; rboxes[r * 4 + 3] = y2;
        rvals[r] = val;
        rlabel[r] = (int)lab;
        out[TOPK * 5 + r] = (float)lab;          // labels (unmasked in reference)
    }
}

// per-class greedy NMS: suppression is exactly class-local because the reference's
// label*4096 offset separates classes by >= 4096-1333 while clipped boxes are <=1333 wide.
__global__ void __launch_bounds__(256) k_nms(const float* __restrict__ rboxes,
                                             const float* __restrict__ rvals,
                                             const int* __restrict__ rlabel,
                                             float* __restrict__ out) {
    int c = blockIdx.x + 1;                     // labels 1..80 (class 0 filtered)
    __shared__ unsigned short mem[TOPK];
    __shared__ unsigned char keepL[TOPK];
    __shared__ u32 ps[256];
    __shared__ u32 mtot;
    int t = threadIdx.x;
    int r0 = t * 16;
    u32 cl = 0;
    for (int r = r0; r < r0 + 16; r++) cl += (rlabel[r] == c) ? 1u : 0u;
    ps[t] = cl;
    __syncthreads();
    if (t == 0) {
        u32 acc = 0;
        for (int q = 0; q < 256; q++) { u32 v = ps[q]; ps[q] = acc; acc += v; }
        mtot = acc;
    }
    __syncthreads();
    u32 base = ps[t];
    for (int r = r0; r < r0 + 16; r++)
        if (rlabel[r] == c) mem[base++] = (unsigned short)r;  // stable: rank-ascending
    u32 m = mtot;
    for (u32 q = t; q < m; q += 256) keepL[q] = 1;
    __syncthreads();

    float off = (float)c * 4096.0f;             // replicate reference's f32 offset rounding
    for (u32 i = 0; i < m; i++) {
        __syncthreads();
        if (!keepL[i]) continue;                // uniform branch
        int ri = mem[i];
        float ix1 = rboxes[ri * 4 + 0] + off, iy1 = rboxes[ri * 4 + 1] + off;
        float ix2 = rboxes[ri * 4 + 2] + off, iy2 = rboxes[ri * 4 + 3] + off;
        float iarea = (ix2 - ix1) * (iy2 - iy1);
        for (u32 jj = i + 1 + t; jj < m; jj += 256) {
            if (!keepL[jj]) continue;
            int rj = mem[jj];
            float jx1 = rboxes[rj * 4 + 0] + off, jy1 = rboxes[rj * 4 + 1] + off;
            float jx2 = rboxes[rj * 4 + 2] + off, jy2 = rboxes[rj * 4 + 3] + off;
            float iw = fmaxf(fminf(ix2, jx2) - fmaxf(ix1, jx1), 0.0f);
            float ih = fmaxf(fminf(iy2, jy2) - fmaxf(iy1, jy1), 0.0f);
            float inter = iw * ih;
            float jarea = (jx2 - jx1) * (jy2 - jy1);
            float iou = inter / (iarea + jarea - inter + 1e-9f);
            if (iou > 0.5f) keepL[jj] = 0;
        }
    }
    __syncthreads();
    for (u32 q = t; q < m; q += 256) {
        int r = mem[q];
        int k = keepL[q];
        out[TOPK * 6 + r] = k ? 1.0f : 0.0f;
        float* d = out + (size_t)r * 5;
        if (k) {
            d[0] = rboxes[r * 4 + 0]; d[1] = rboxes[r * 4 + 1];
            d[2] = rboxes[r * 4 + 2]; d[3] = rboxes[r * 4 + 3];
            d[4] = rvals[r];
        } else {
            d[0] = 0; d[1] = 0; d[2] = 0; d[3] = 0; d[4] = 0;
        }
    }
}

extern "C" void kernel_launch(void* const* d_in, const int* in_sizes, int n_in,
                              void* d_out, int out_size, void* d_ws, size_t ws_size,
                              hipStream_t stream) {
    const float* x = (const float*)d_in[0];
    const float* boxes = (const float*)d_in[1];
    float* out = (float*)d_out;

    u32* W = (u32*)d_ws;
    u32* cnt = W;                                 // 16
    u32* hist1 = W + 16;                          // 65536
    u32* hist2 = W + 16 + 65536;                  // 65536
    u64* sel = (u64*)(W + 16 + 2 * 65536);        // 4096 u64 (8B aligned)
    u32* candKey = W + 16 + 2 * 65536 + 2 * TOPK; // MAXCAND
    u32* candIdx = candKey + MAXCAND;
    u32* eqI = candIdx + MAXCAND;
    float* rboxes = (float*)(eqI + EQCAP);
    float* rvals = rboxes + 4 * TOPK;
    int* rlabel = (int*)(rvals + TOPK);

    const int nzero = 16 + 2 * 65536;             // cnt + hist1 + hist2
    k_zero<<<(nzero + 255) / 256, 256, 0, stream>>>(W, nzero);
    k_cand<<<CAND_GRID, CAND_THREADS, 0, stream>>>(x, candKey, candIdx, cnt, hist1);
    k_cut1<<<1, 1024, 0, stream>>>(hist1, cnt);
    k_hist2<<<256, 256, 0, stream>>>(candKey, cnt, hist2);
    k_cut2<<<1, 1024, 0, stream>>>(hist2, cnt);
    k_collect<<<COLL_GRID, 256, 0, stream>>>(candKey, candIdx, cnt, sel, eqI);
    k_sort<<<1, 1024, 0, stream>>>(sel, eqI, cnt, boxes, rboxes, rvals, rlabel, out);
    k_nms<<<80, 256, 0, stream>>>(rboxes, rvals, rlabel, out);
}

// Round 6
// 210.418 us; speedup vs baseline: 3.2244x; 1.1775x over previous
//
#include <hip/hip_runtime.h>

#pragma clang fp contract(off)

typedef unsigned int u32;
typedef unsigned long long u64;
typedef long long i64;

#define N_ROWS 32768
#define NCLS 81
#define TOPK 4096
#define MAXCAND 327680
#define EQCAP 8192
#define IMGW_M1 1332.0f
#define IMGH_M1 799.0f

// k_cand geometry: 8 threads/row, 32 rows/block, 1024 blocks
#define CAND_THREADS 256
#define RPB 32
#define CAND_GRID (N_ROWS / RPB)          // 1024
#define CPT 11                            // max classes/thread (thread 7: 11, others 10)
#define BLK_CAND_CAP 640                  // 32 rows * <=19 cand/row = 608 max
#define ROW_F4 ((RPB * NCLS) / 4)         // 648 float4 per block slice (exactly)

// histogram level-1: keys are f32 bits of p in (0.05, 1.0] -> hi16 in [0x3D4C, 0x3F80]
#define H1_BASE 0x3D4Cu
#define H1_BINS 576                       // covers 0x3D4C..0x3F80 (565) + pad
#define HIST1_GRID 64

// k_collect geometry
#define COLL_GRID 512
#define COLL_CAP 640                      // MAXCAND / COLL_GRID

// ---------------- ws layout (u32 units) ----------------
// [0,16)            cnt: 0=candCount 1=selCount 2=eqCount 3=- 4=- 5=cutKey 6=numFromEqual
// [16, +576)        hist1g (windowed, 565 used)
// [592, +65536)     hist2
// [66128, +8192)    sel (u64[4096])
// [74320, +MAXCAND) candKey
// [+MAXCAND)        candIdx
// [+EQCAP)          eqIdx
// [+16384)          rboxes (f32 4096x4)
// [+4096)           rvals
// [+4096)           rlabel (i32)

__global__ void k_zero(u32* __restrict__ p, int n) {
    int i = blockIdx.x * blockDim.x + threadIdx.x;
    if (i < n) p[i] = 0u;
}

// fast f64 exp for d <= 0 (clamped at -45: dropped terms < 3e-20 never matter
// vs sum >= 1). Cody-Waite reduction + Taylor-13. Relative error ~3e-16 —
// decisions have >= f32-ulp (6e-8) margins.
__device__ inline double fast_exp_neg(double d) {
    if (d < -45.0) return 0.0;
    const double L2E    = 1.4426950408889634074;
    const double LN2_HI = 6.93147180369123816490e-01;
    const double LN2_LO = 1.90821492927058770002e-10;
    double n = __builtin_rint(d * L2E);
    double r = __builtin_fma(-n, LN2_HI, d);
    r = __builtin_fma(-n, LN2_LO, r);
    double p = 1.0 / 6227020800.0;
    p = __builtin_fma(p, r, 1.0 / 479001600.0);
    p = __builtin_fma(p, r, 1.0 / 39916800.0);
    p = __builtin_fma(p, r, 1.0 / 3628800.0);
    p = __builtin_fma(p, r, 1.0 / 362880.0);
    p = __builtin_fma(p, r, 1.0 / 40320.0);
    p = __builtin_fma(p, r, 1.0 / 5040.0);
    p = __builtin_fma(p, r, 1.0 / 720.0);
    p = __builtin_fma(p, r, 1.0 / 120.0);
    p = __builtin_fma(p, r, 1.0 / 24.0);
    p = __builtin_fma(p, r, 1.0 / 6.0);
    p = __builtin_fma(p, r, 0.5);
    p = __builtin_fma(p, r, 1.0);
    p = __builtin_fma(p, r, 1.0);
    i64 ni = (i64)n;
    double sc = __longlong_as_double((i64)(1023 + ni) << 52);
    return p * sc;
}

// softmax + threshold + compaction ONLY (no histogram atomics here).
// Two-pass recompute: no e[] array -> no spill pressure. Identical arithmetic
// order to the passing R5 kernel -> bit-identical decisions.
__global__ void __launch_bounds__(256) k_cand(const float* __restrict__ x,
                                              u32* __restrict__ candKey,
                                              u32* __restrict__ candIdx,
                                              u32* __restrict__ cnt) {
    __shared__ float4 lx4[ROW_F4];
    __shared__ u32 lK[BLK_CAND_CAP];
    __shared__ u32 lI[BLK_CAND_CAP];
    __shared__ u32 lcnt;
    __shared__ u32 gbaseSh;
    float* lx = (float*)lx4;
    const int t = threadIdx.x;
    if (t == 0) lcnt = 0;

    // coalesced global -> LDS staging (32*81*4 B = 648 float4 exactly)
    const float4* xv = (const float4*)x + (size_t)blockIdx.x * ROW_F4;
    for (int i = t; i < ROW_F4; i += CAND_THREADS) lx4[i] = xv[i];
    __syncthreads();

    const int rl = t >> 3;                        // local row 0..31
    const int q = t & 7;
    const int c0 = q * 10;                        // thread 7 covers 70..80
    const int cEff = (q == 7) ? 11 : 10;
    const int row = blockIdx.x * RPB + rl;
    const float* xr = lx + rl * NCLS;

    float v[CPT];
    #pragma unroll
    for (int i = 0; i < CPT; i++) v[i] = (i < cEff) ? xr[c0 + i] : -1.0e30f;

    float m = v[0];
    #pragma unroll
    for (int i = 1; i < CPT; i++) m = fmaxf(m, v[i]);
    m = fmaxf(m, __shfl_xor(m, 1));
    m = fmaxf(m, __shfl_xor(m, 2));
    m = fmaxf(m, __shfl_xor(m, 4));               // row max across 8-lane group

    // pass 1: sum (same sequential order as before -> identical bits)
    double s = 0.0;
    #pragma unroll
    for (int i = 0; i < CPT; i++) {
        if (i < cEff) {
            float d = v[i] - m;                   // f32 subtract, as reference
            s += fast_exp_neg((double)d);
        }
    }
    s += __shfl_xor(s, 1);
    s += __shfl_xor(s, 2);
    s += __shfl_xor(s, 4);                        // butterfly: identical s in group

    // float(p)>0.05f  <=>  p > 0.05f + 2^-29 (half-ulp midpoint); f64 mul, no div
    const double THRMID = (double)0.05f + 0x1.0p-29;
    double ethr = THRMID * s;
    // pass 2: recompute e_i (identical instruction sequence -> identical bits)
    #pragma unroll
    for (int i = 0; i < CPT; i++) {
        int c = c0 + i;
        if (i < cEff && c != 0) {
            float d = v[i] - m;
            double e = fast_exp_neg((double)d);
            if (e > ethr) {
                float pf = (float)(e / s);        // exact f64 division, rare
                u32 slot = atomicAdd(&lcnt, 1u);
                lK[slot] = __float_as_uint(pf);
                lI[slot] = (u32)(row * NCLS + c);
            }
        }
    }
    __syncthreads();
    u32 tot = lcnt;
    if (t == 0) gbaseSh = tot ? atomicAdd(&cnt[0], tot) : 0u;
    __syncthreads();
    u32 gbase = gbaseSh;
    for (u32 i = t; i < tot; i += CAND_THREADS) {
        u32 g = gbase + i;
        if (g < MAXCAND) {
            candKey[g] = lK[i];
            candIdx[g] = lI[i];
        }
    }
}

// LDS-privatized level-1 histogram: 565 bins fit in 2.3 KB. 64 big blocks ->
// per-bin global-merge depth <= 64 (vs ~500-deep same-address atomics before).
__global__ void __launch_bounds__(256) k_hist1(const u32* __restrict__ candKey,
                                               const u32* __restrict__ cnt,
                                               u32* __restrict__ hist1g) {
    __shared__ u32 lh[H1_BINS];
    int t = threadIdx.x;
    for (int i = t; i < H1_BINS; i += 256) lh[i] = 0;
    __syncthreads();
    u32 n = cnt[0] < (u32)MAXCAND ? cnt[0] : (u32)MAXCAND;
    u32 stride = HIST1_GRID * 256;
    for (u32 i = blockIdx.x * 256 + t; i < n; i += stride) {
        u32 b = (candKey[i] >> 16) - H1_BASE;
        if (b < (u32)H1_BINS) atomicAdd(&lh[b], 1u);
    }
    __syncthreads();
    for (int i = t; i < H1_BINS; i += 256) {
        u32 v = lh[i];
        if (v) atomicAdd(&hist1g[i], v);
    }
}

// fused cutoff finder: level-1 scan + level-2 histogram + level-2 scan.
// Single block => its own global atomics are visible after __syncthreads.
__global__ void __launch_bounds__(1024) k_mid(const u32* __restrict__ candKey,
                                              u32* __restrict__ cnt,
                                              const u32* __restrict__ hist1g,
                                              u32* __restrict__ hist2) {
    __shared__ u32 cs[1024];
    __shared__ u32 sB, sAcc, sFound;
    int t = threadIdx.x;
    if (t == 0) sFound = 0;
    cs[t] = (t < H1_BINS) ? hist1g[t] : 0u;
    __syncthreads();
    for (int d = 1; d < 1024; d <<= 1) {          // inclusive suffix sum
        u32 v = (t + d < 1024) ? cs[t + d] : 0u;
        __syncthreads();
        cs[t] += v;
        __syncthreads();
    }
    u32 S_t = cs[t];
    u32 S_next = (t < 1023) ? cs[t + 1] : 0u;
    if (S_next < TOPK && S_t >= TOPK) {           // exactly one thread (1 bin each)
        sB = (u32)t; sAcc = S_next; sFound = 1;
    }
    __syncthreads();
    if (!sFound) {                                // degenerate: < TOPK candidates
        if (t == 0) { cnt[5] = 0u; cnt[6] = 0u; }
        return;
    }
    u32 Bhi = sB + H1_BASE;
    u32 n = cnt[0] < (u32)MAXCAND ? cnt[0] : (u32)MAXCAND;
    for (u32 i = t; i < n; i += 1024) {           // level-2 histogram (~n/565 hits)
        u32 k = candKey[i];
        if ((k >> 16) == Bhi) atomicAdd(&hist2[k & 0xFFFFu], 1u);
    }
    __syncthreads();
    u32 C = sAcc;
    u32 s2 = 0;
    const u32* hp = hist2 + t * 64;
    for (int b = 0; b < 64; b++) s2 += hp[b];
    cs[t] = s2;
    __syncthreads();
    for (int d = 1; d < 1024; d <<= 1) {
        u32 v = (t + d < 1024) ? cs[t + d] : 0u;
        __syncthreads();
        cs[t] += v;
        __syncthreads();
    }
    S_t = cs[t];
    S_next = (t < 1023) ? cs[t + 1] : 0u;
    if (C + S_next < TOPK && C + S_t >= TOPK) {
        u32 acc = C + S_next;
        int L = t * 64;
        for (int b = t * 64 + 63; b >= t * 64; b--) {
            u32 h = hist2[b];
            if (acc + h >= TOPK) { L = b; break; }
            acc += h;
        }
        cnt[5] = (Bhi << 16) | (u32)L;            // exact cutoff key
        cnt[6] = TOPK - acc;                      // take from ==cutoff set
    }
}

// block-aggregated collect: LDS staging + ONE global atomic per block per list
__global__ void __launch_bounds__(256) k_collect(const u32* __restrict__ candKey,
                                                 const u32* __restrict__ candIdx,
                                                 u32* __restrict__ cnt,
                                                 u64* __restrict__ sel,
                                                 u32* __restrict__ eqI) {
    __shared__ u64 sStage[COLL_CAP];
    __shared__ u32 eStage[COLL_CAP];
    __shared__ u32 sc, ec, sb, eb;
    int t = threadIdx.x;
    if (t == 0) { sc = 0; ec = 0; }
    __syncthreads();
    u32 n = cnt[0] < (u32)MAXCAND ? cnt[0] : (u32)MAXCAND;
    u32 chunk = (n + COLL_GRID - 1) / COLL_GRID;  // <= 640 by construction
    u32 lo = blockIdx.x * chunk;
    u32 hi = lo + chunk; if (hi > n) hi = n;
    u32 cut = cnt[5];
    for (u32 i = lo + t; i < hi; i += 256) {
        u32 k = candKey[i];
        if (k > cut) {
            u32 p = atomicAdd(&sc, 1u);
            sStage[p] = ((u64)k << 32) | (u64)(0xFFFFFFFFu - candIdx[i]);
        } else if (k == cut) {
            u32 e2 = atomicAdd(&ec, 1u);
            eStage[e2] = candIdx[i];
        }
    }
    __syncthreads();
    if (t == 0) {
        sb = sc ? atomicAdd(&cnt[1], sc) : 0u;
        eb = ec ? atomicAdd(&cnt[2], ec) : 0u;
    }
    __syncthreads();
    for (u32 i = t; i < sc; i += 256) { u32 g = sb + i; if (g < TOPK) sel[g] = sStage[i]; }
    for (u32 i = t; i < ec; i += 256) { u32 g = eb + i; if (g < EQCAP) eqI[g] = eStage[i]; }
}

// eq-fill + bitonic sort 4096 u64 (val desc, idx asc) + gather/clip/emit
__global__ void __launch_bounds__(1024) k_sort(const u64* __restrict__ sel,
                                               const u32* __restrict__ eqI,
                                               const u32* __restrict__ cnt,
                                               const float* __restrict__ boxes,
                                               float* __restrict__ rboxes, float* __restrict__ rvals,
                                               int* __restrict__ rlabel, float* __restrict__ out) {
    __shared__ u64 lds[TOPK];
    int t = threadIdx.x;
    u32 nsel = cnt[1] < (u32)TOPK ? cnt[1] : (u32)TOPK;
    for (int i = t; i < TOPK; i += 1024) lds[i] = ((u32)i < nsel) ? sel[i] : 0ull;
    __syncthreads();
    {   // rank ==cutoff candidates by ascending index
        u32 mm = cnt[2] < (u32)EQCAP ? cnt[2] : (u32)EQCAP;
        u32 need = cnt[6];
        u32 base = cnt[1];
        u32 cut = cnt[5];
        for (u32 j = t; j < mm; j += 1024) {
            u32 v = eqI[j];
            u32 rank = 0;
            for (u32 k = 0; k < mm; k++) rank += (eqI[k] < v) ? 1u : 0u;  // unique
            if (rank < need && base + rank < TOPK)
                lds[base + rank] = ((u64)cut << 32) | (u64)(0xFFFFFFFFu - v);
        }
    }
    __syncthreads();
    for (u32 k = 2; k <= TOPK; k <<= 1) {
        for (u32 j = k >> 1; j > 0; j >>= 1) {
            for (u32 q = t; q < TOPK / 2; q += 1024) {
                u32 i = ((q & ~(j - 1)) << 1) | (q & (j - 1));
                u32 p = i | j;
                u64 a = lds[i], b = lds[p];
                bool up = ((i & k) == 0);
                bool sw = up ? (a < b) : (a > b);   // descending overall
                if (sw) { lds[i] = b; lds[p] = a; }
            }
            __syncthreads();
        }
    }
    for (int r = t; r < TOPK; r += 1024) {
        u64 key = lds[r];
        if (key == 0ull) {  // underfill guard
            rboxes[r * 4 + 0] = 0; rboxes[r * 4 + 1] = 0; rboxes[r * 4 + 2] = 0; rboxes[r * 4 + 3] = 0;
            rvals[r] = 0.0f; rlabel[r] = 0;
            out[TOPK * 5 + r] = 0.0f;
            out[TOPK * 6 + r] = 0.0f;
            float* d = out + (size_t)r * 5;
            d[0] = 0; d[1] = 0; d[2] = 0; d[3] = 0; d[4] = 0;
            continue;
        }
        u32 idx = 0xFFFFFFFFu - (u32)(key & 0xFFFFFFFFull);
        float val = __uint_as_float((u32)(key >> 32));
        u32 bi = idx / NCLS;
        u32 lab = idx % NCLS;
        const float* bp = boxes + (size_t)bi * 4;
        float x1 = fminf(fmaxf(bp[0], 0.0f), IMGW_M1);
        float y1 = fminf(fmaxf(bp[1], 0.0f), IMGH_M1);
        float x2 = fminf(fmaxf(bp[2], 0.0f), IMGW_M1);
        float y2 = fminf(fmaxf(bp[3], 0.0f), IMGH_M1);
        rboxes[r * 4 + 0] = x1; rboxes[r * 4 + 1] = y1;
        rboxes[r * 4 + 2] = x2; rboxes[r * 4 + 3] = y2;
        rvals[r] = val;
        rlabel[r] = (int)lab;
        out[TOPK * 5 + r] = (float)lab;          // labels (unmasked in reference)
    }
}

// per-class greedy NMS: suppression is exactly class-local because the reference's
// label*4096 offset separates classes by >= 4096-1333 while clipped boxes are <=1333 wide.
__global__ void __launch_bounds__(256) k_nms(const float* __restrict__ rboxes,
                                             const float* __restrict__ rvals,
                                             const int* __restrict__ rlabel,
                                             float* __restrict__ out) {
    int c = blockIdx.x + 1;                     // labels 1..80 (class 0 filtered)
    __shared__ unsigned short mem[TOPK];
    __shared__ unsigned char keepL[TOPK];
    __shared__ u32 ps[256];
    __shared__ u32 mtot;
    int t = threadIdx.x;
    int r0 = t * 16;
    u32 cl = 0;
    for (int r = r0; r < r0 + 16; r++) cl += (rlabel[r] == c) ? 1u : 0u;
    ps[t] = cl;
    __syncthreads();
    if (t == 0) {
        u32 acc = 0;
        for (int q = 0; q < 256; q++) { u32 v = ps[q]; ps[q] = acc; acc += v; }
        mtot = acc;
    }
    __syncthreads();
    u32 base = ps[t];
    for (int r = r0; r < r0 + 16; r++)
        if (rlabel[r] == c) mem[base++] = (unsigned short)r;  // stable: rank-ascending
    u32 m = mtot;
    for (u32 q = t; q < m; q += 256) keepL[q] = 1;
    __syncthreads();

    float off = (float)c * 4096.0f;             // replicate reference's f32 offset rounding
    for (u32 i = 0; i < m; i++) {
        __syncthreads();
        if (!keepL[i]) continue;                // uniform branch
        int ri = mem[i];
        float ix1 = rboxes[ri * 4 + 0] + off, iy1 = rboxes[ri * 4 + 1] + off;
        float ix2 = rboxes[ri * 4 + 2] + off, iy2 = rboxes[ri * 4 + 3] + off;
        float iarea = (ix2 - ix1) * (iy2 - iy1);
        for (u32 jj = i + 1 + t; jj < m; jj += 256) {
            if (!keepL[jj]) continue;
            int rj = mem[jj];
            float jx1 = rboxes[rj * 4 + 0] + off, jy1 = rboxes[rj * 4 + 1] + off;
            float jx2 = rboxes[rj * 4 + 2] + off, jy2 = rboxes[rj * 4 + 3] + off;
            float iw = fmaxf(fminf(ix2, jx2) - fmaxf(ix1, jx1), 0.0f);
            float ih = fmaxf(fminf(iy2, jy2) - fmaxf(iy1, jy1), 0.0f);
            float inter = iw * ih;
            float jarea = (jx2 - jx1) * (jy2 - jy1);
            float iou = inter / (iarea + jarea - inter + 1e-9f);
            if (iou > 0.5f) keepL[jj] = 0;
        }
    }
    __syncthreads();
    for (u32 q = t; q < m; q += 256) {
        int r = mem[q];
        int k = keepL[q];
        out[TOPK * 6 + r] = k ? 1.0f : 0.0f;
        float* d = out + (size_t)r * 5;
        if (k) {
            d[0] = rboxes[r * 4 + 0]; d[1] = rboxes[r * 4 + 1];
            d[2] = rboxes[r * 4 + 2]; d[3] = rboxes[r * 4 + 3];
            d[4] = rvals[r];
        } else {
            d[0] = 0; d[1] = 0; d[2] = 0; d[3] = 0; d[4] = 0;
        }
    }
}

extern "C" void kernel_launch(void* const* d_in, const int* in_sizes, int n_in,
                              void* d_out, int out_size, void* d_ws, size_t ws_size,
                              hipStream_t stream) {
    const float* x = (const float*)d_in[0];
    const float* boxes = (const float*)d_in[1];
    float* out = (float*)d_out;

    u32* W = (u32*)d_ws;
    u32* cnt = W;                                 // 16
    u32* hist1g = W + 16;                         // 576
    u32* hist2 = W + 16 + H1_BINS;                // 65536
    u64* sel = (u64*)(W + 16 + H1_BINS + 65536);  // 4096 u64 (8B aligned: 66128*4 % 8 == 0)
    u32* candKey = W + 16 + H1_BINS + 65536 + 2 * TOPK;
    u32* candIdx = candKey + MAXCAND;
    u32* eqI = candIdx + MAXCAND;
    float* rboxes = (float*)(eqI + EQCAP);
    float* rvals = rboxes + 4 * TOPK;
    int* rlabel = (int*)(rvals + TOPK);

    const int nzero = 16 + H1_BINS + 65536;       // cnt + hist1g + hist2
    k_zero<<<(nzero + 255) / 256, 256, 0, stream>>>(W, nzero);
    k_cand<<<CAND_GRID, CAND_THREADS, 0, stream>>>(x, candKey, candIdx, cnt);
    k_hist1<<<HIST1_GRID, 256, 0, stream>>>(candKey, cnt, hist1g);
    k_mid<<<1, 1024, 0, stream>>>(candKey, cnt, hist1g, hist2);
    k_collect<<<COLL_GRID, 256, 0, stream>>>(candKey, candIdx, cnt, sel, eqI);
    k_sort<<<1, 1024, 0, stream>>>(sel, eqI, cnt, boxes, rboxes, rvals, rlabel, out);
    k_nms<<<80, 256, 0, stream>>>(rboxes, rvals, rlabel, out);
}

// Round 7
// 182.335 us; speedup vs baseline: 3.7210x; 1.1540x over previous
//
#include <hip/hip_runtime.h>

#pragma clang fp contract(off)

typedef unsigned int u32;
typedef unsigned long long u64;
typedef long long i64;

#define N_ROWS 32768
#define NCLS 81
#define TOPK 4096
#define MAXCAND 327680
#define EQCAP 8192
#define IMGW_M1 1332.0f
#define IMGH_M1 799.0f

// k_cand geometry: 8 threads/row, 32 rows/block, 1024 blocks
#define CAND_THREADS 256
#define RPB 32
#define CAND_GRID (N_ROWS / RPB)          // 1024
#define CPT 11                            // max classes/thread (thread 7: 11, others 10)
#define BLK_CAND_CAP 640                  // 32 rows * <=19 cand/row = 608 max
#define ROW_F4 ((RPB * NCLS) / 4)         // 648 float4 per block slice (exactly)

// histogram level-1: keys are f32 bits of p in (0.05, 1.0] -> hi16 in [0x3D4C, 0x3F80]
#define H1_BASE 0x3D4Cu
#define H1_BINS 576                       // covers 0x3D4C..0x3F80 (565) + pad
#define HIST1_GRID 64

// k_collect geometry
#define COLL_GRID 512
#define COLL_CAP 640                      // MAXCAND / COLL_GRID

// ---------------- ws layout (u32 units) ----------------
// [0,16)            cnt: 0=candCount 1=selCount 2=eqCount 3=- 4=- 5=cutKey 6=numFromEqual
// [16, +576)        hist1g (windowed, 565 used)
// [592, +65536)     hist2
// [66128, +8192)    sel (u64[4096])
// [74320, +MAXCAND) candKey
// [+MAXCAND)        candIdx
// [+EQCAP)          eqIdx
// [+16384)          rboxes (f32 4096x4)
// [+4096)           rvals
// [+4096)           rlabel (i32)

__global__ void k_zero(u32* __restrict__ p, int n) {
    int i = blockIdx.x * blockDim.x + threadIdx.x;
    if (i < n) p[i] = 0u;
}

// fast f64 exp for d <= 0 (clamped at -45: dropped terms < 3e-20 never matter
// vs sum >= 1). Cody-Waite reduction + Taylor-13. Relative error ~3e-16 —
// decisions have >= f32-ulp (6e-8) margins.
__device__ inline double fast_exp_neg(double d) {
    if (d < -45.0) return 0.0;
    const double L2E    = 1.4426950408889634074;
    const double LN2_HI = 6.93147180369123816490e-01;
    const double LN2_LO = 1.90821492927058770002e-10;
    double n = __builtin_rint(d * L2E);
    double r = __builtin_fma(-n, LN2_HI, d);
    r = __builtin_fma(-n, LN2_LO, r);
    double p = 1.0 / 6227020800.0;
    p = __builtin_fma(p, r, 1.0 / 479001600.0);
    p = __builtin_fma(p, r, 1.0 / 39916800.0);
    p = __builtin_fma(p, r, 1.0 / 3628800.0);
    p = __builtin_fma(p, r, 1.0 / 362880.0);
    p = __builtin_fma(p, r, 1.0 / 40320.0);
    p = __builtin_fma(p, r, 1.0 / 5040.0);
    p = __builtin_fma(p, r, 1.0 / 720.0);
    p = __builtin_fma(p, r, 1.0 / 120.0);
    p = __builtin_fma(p, r, 1.0 / 24.0);
    p = __builtin_fma(p, r, 1.0 / 6.0);
    p = __builtin_fma(p, r, 0.5);
    p = __builtin_fma(p, r, 1.0);
    p = __builtin_fma(p, r, 1.0);
    i64 ni = (i64)n;
    double sc = __longlong_as_double((i64)(1023 + ni) << 52);
    return p * sc;
}

// softmax + threshold + compaction ONLY. Two-pass recompute (no spills).
// Identical arithmetic order to the passing R6 kernel -> bit-identical decisions.
__global__ void __launch_bounds__(256) k_cand(const float* __restrict__ x,
                                              u32* __restrict__ candKey,
                                              u32* __restrict__ candIdx,
                                              u32* __restrict__ cnt) {
    __shared__ float4 lx4[ROW_F4];
    __shared__ u32 lK[BLK_CAND_CAP];
    __shared__ u32 lI[BLK_CAND_CAP];
    __shared__ u32 lcnt;
    __shared__ u32 gbaseSh;
    float* lx = (float*)lx4;
    const int t = threadIdx.x;
    if (t == 0) lcnt = 0;

    const float4* xv = (const float4*)x + (size_t)blockIdx.x * ROW_F4;
    for (int i = t; i < ROW_F4; i += CAND_THREADS) lx4[i] = xv[i];
    __syncthreads();

    const int rl = t >> 3;
    const int q = t & 7;
    const int c0 = q * 10;
    const int cEff = (q == 7) ? 11 : 10;
    const int row = blockIdx.x * RPB + rl;
    const float* xr = lx + rl * NCLS;

    float v[CPT];
    #pragma unroll
    for (int i = 0; i < CPT; i++) v[i] = (i < cEff) ? xr[c0 + i] : -1.0e30f;

    float m = v[0];
    #pragma unroll
    for (int i = 1; i < CPT; i++) m = fmaxf(m, v[i]);
    m = fmaxf(m, __shfl_xor(m, 1));
    m = fmaxf(m, __shfl_xor(m, 2));
    m = fmaxf(m, __shfl_xor(m, 4));

    double s = 0.0;
    #pragma unroll
    for (int i = 0; i < CPT; i++) {
        if (i < cEff) {
            float d = v[i] - m;
            s += fast_exp_neg((double)d);
        }
    }
    s += __shfl_xor(s, 1);
    s += __shfl_xor(s, 2);
    s += __shfl_xor(s, 4);

    const double THRMID = (double)0.05f + 0x1.0p-29;
    double ethr = THRMID * s;
    #pragma unroll
    for (int i = 0; i < CPT; i++) {
        int c = c0 + i;
        if (i < cEff && c != 0) {
            float d = v[i] - m;
            double e = fast_exp_neg((double)d);
            if (e > ethr) {
                float pf = (float)(e / s);
                u32 slot = atomicAdd(&lcnt, 1u);
                lK[slot] = __float_as_uint(pf);
                lI[slot] = (u32)(row * NCLS + c);
            }
        }
    }
    __syncthreads();
    u32 tot = lcnt;
    if (t == 0) gbaseSh = tot ? atomicAdd(&cnt[0], tot) : 0u;
    __syncthreads();
    u32 gbase = gbaseSh;
    for (u32 i = t; i < tot; i += CAND_THREADS) {
        u32 g = gbase + i;
        if (g < MAXCAND) {
            candKey[g] = lK[i];
            candIdx[g] = lI[i];
        }
    }
}

// LDS-privatized level-1 histogram
__global__ void __launch_bounds__(256) k_hist1(const u32* __restrict__ candKey,
                                               const u32* __restrict__ cnt,
                                               u32* __restrict__ hist1g) {
    __shared__ u32 lh[H1_BINS];
    int t = threadIdx.x;
    for (int i = t; i < H1_BINS; i += 256) lh[i] = 0;
    __syncthreads();
    u32 n = cnt[0] < (u32)MAXCAND ? cnt[0] : (u32)MAXCAND;
    u32 stride = HIST1_GRID * 256;
    for (u32 i = blockIdx.x * 256 + t; i < n; i += stride) {
        u32 b = (candKey[i] >> 16) - H1_BASE;
        if (b < (u32)H1_BINS) atomicAdd(&lh[b], 1u);
    }
    __syncthreads();
    for (int i = t; i < H1_BINS; i += 256) {
        u32 v = lh[i];
        if (v) atomicAdd(&hist1g[i], v);
    }
}

// fused cutoff finder: level-1 scan + level-2 histogram + level-2 scan
__global__ void __launch_bounds__(1024) k_mid(const u32* __restrict__ candKey,
                                              u32* __restrict__ cnt,
                                              const u32* __restrict__ hist1g,
                                              u32* __restrict__ hist2) {
    __shared__ u32 cs[1024];
    __shared__ u32 sB, sAcc, sFound;
    int t = threadIdx.x;
    if (t == 0) sFound = 0;
    cs[t] = (t < H1_BINS) ? hist1g[t] : 0u;
    __syncthreads();
    for (int d = 1; d < 1024; d <<= 1) {
        u32 v = (t + d < 1024) ? cs[t + d] : 0u;
        __syncthreads();
        cs[t] += v;
        __syncthreads();
    }
    u32 S_t = cs[t];
    u32 S_next = (t < 1023) ? cs[t + 1] : 0u;
    if (S_next < TOPK && S_t >= TOPK) {
        sB = (u32)t; sAcc = S_next; sFound = 1;
    }
    __syncthreads();
    if (!sFound) {
        if (t == 0) { cnt[5] = 0u; cnt[6] = 0u; }
        return;
    }
    u32 Bhi = sB + H1_BASE;
    u32 n = cnt[0] < (u32)MAXCAND ? cnt[0] : (u32)MAXCAND;
    for (u32 i = t; i < n; i += 1024) {
        u32 k = candKey[i];
        if ((k >> 16) == Bhi) atomicAdd(&hist2[k & 0xFFFFu], 1u);
    }
    __syncthreads();
    u32 C = sAcc;
    u32 s2 = 0;
    const u32* hp = hist2 + t * 64;
    for (int b = 0; b < 64; b++) s2 += hp[b];
    cs[t] = s2;
    __syncthreads();
    for (int d = 1; d < 1024; d <<= 1) {
        u32 v = (t + d < 1024) ? cs[t + d] : 0u;
        __syncthreads();
        cs[t] += v;
        __syncthreads();
    }
    S_t = cs[t];
    S_next = (t < 1023) ? cs[t + 1] : 0u;
    if (C + S_next < TOPK && C + S_t >= TOPK) {
        u32 acc = C + S_next;
        int L = t * 64;
        for (int b = t * 64 + 63; b >= t * 64; b--) {
            u32 h = hist2[b];
            if (acc + h >= TOPK) { L = b; break; }
            acc += h;
        }
        cnt[5] = (Bhi << 16) | (u32)L;
        cnt[6] = TOPK - acc;
    }
}

// block-aggregated collect
__global__ void __launch_bounds__(256) k_collect(const u32* __restrict__ candKey,
                                                 const u32* __restrict__ candIdx,
                                                 u32* __restrict__ cnt,
                                                 u64* __restrict__ sel,
                                                 u32* __restrict__ eqI) {
    __shared__ u64 sStage[COLL_CAP];
    __shared__ u32 eStage[COLL_CAP];
    __shared__ u32 sc, ec, sb, eb;
    int t = threadIdx.x;
    if (t == 0) { sc = 0; ec = 0; }
    __syncthreads();
    u32 n = cnt[0] < (u32)MAXCAND ? cnt[0] : (u32)MAXCAND;
    u32 chunk = (n + COLL_GRID - 1) / COLL_GRID;
    u32 lo = blockIdx.x * chunk;
    u32 hi = lo + chunk; if (hi > n) hi = n;
    u32 cut = cnt[5];
    for (u32 i = lo + t; i < hi; i += 256) {
        u32 k = candKey[i];
        if (k > cut) {
            u32 p = atomicAdd(&sc, 1u);
            sStage[p] = ((u64)k << 32) | (u64)(0xFFFFFFFFu - candIdx[i]);
        } else if (k == cut) {
            u32 e2 = atomicAdd(&ec, 1u);
            eStage[e2] = candIdx[i];
        }
    }
    __syncthreads();
    if (t == 0) {
        sb = sc ? atomicAdd(&cnt[1], sc) : 0u;
        eb = ec ? atomicAdd(&cnt[2], ec) : 0u;
    }
    __syncthreads();
    for (u32 i = t; i < sc; i += 256) { u32 g = sb + i; if (g < TOPK) sel[g] = sStage[i]; }
    for (u32 i = t; i < ec; i += 256) { u32 g = eb + i; if (g < EQCAP) eqI[g] = eStage[i]; }
}

// counting-rank (replaces bitonic sort): hi16-bin histogram + suffix-sum +
// bin-grouped scatter + within-bin linear rank over low 48 bits
// (lo16 key || ~idx == value-desc, idx-asc). Composites unique => exact
// permutation, identical ordering to a full sort. Emits ranked outputs.
__global__ void __launch_bounds__(1024) k_rank(const u64* __restrict__ sel,
                                               const u32* __restrict__ eqI,
                                               const u32* __restrict__ cnt,
                                               const float* __restrict__ boxes,
                                               float* __restrict__ rboxes, float* __restrict__ rvals,
                                               int* __restrict__ rlabel, float* __restrict__ out) {
    __shared__ u64 binned[TOPK];      // 32 KB
    __shared__ u32 hist[H1_BINS];
    __shared__ u32 base[H1_BINS];
    __shared__ u32 cur[H1_BINS];
    __shared__ u32 cs[1024];
    int t = threadIdx.x;
    u32 nsel = cnt[1] < (u32)TOPK ? cnt[1] : (u32)TOPK;
    u32 m = cnt[2] < (u32)EQCAP ? cnt[2] : (u32)EQCAP;
    u32 need = cnt[6];
    if (nsel + need > (u32)TOPK) need = TOPK - nsel;
    u32 cut = cnt[5];

    for (int i = t; i < H1_BINS; i += 1024) { hist[i] = 0; cur[i] = 0; }
    // defensive zero-init of all ranked outputs (covers degenerate underfill)
    for (int r = t; r < TOPK; r += 1024) {
        rboxes[r * 4 + 0] = 0; rboxes[r * 4 + 1] = 0;
        rboxes[r * 4 + 2] = 0; rboxes[r * 4 + 3] = 0;
        rvals[r] = 0.0f; rlabel[r] = 0;
        out[TOPK * 5 + r] = 0.0f;
        out[TOPK * 6 + r] = 0.0f;
        float* d = out + (size_t)r * 5;
        d[0] = 0; d[1] = 0; d[2] = 0; d[3] = 0; d[4] = 0;
    }
    __syncthreads();
    for (u32 i = t; i < nsel; i += 1024) {
        u32 b = (u32)(sel[i] >> 48) - H1_BASE;
        atomicAdd(&hist[b], 1u);
    }
    __syncthreads();
    cs[t] = (t < H1_BINS) ? hist[t] : 0u;
    __syncthreads();
    for (int d = 1; d < 1024; d <<= 1) {          // inclusive suffix sum
        u32 v = (t + d < 1024) ? cs[t + d] : 0u;
        __syncthreads();
        cs[t] += v;
        __syncthreads();
    }
    if (t < H1_BINS) base[t] = (t + 1 < 1024) ? cs[t + 1] : 0u;  // # in bins > t
    __syncthreads();
    for (u32 i = t; i < nsel; i += 1024) {
        u64 c = sel[i];
        u32 b = (u32)(c >> 48) - H1_BASE;
        u32 p = base[b] + atomicAdd(&cur[b], 1u);
        binned[p] = c;
    }
    __syncthreads();

    for (u32 p = t; p < nsel; p += 1024) {
        u64 c = binned[p];
        u32 b = (u32)(c >> 48) - H1_BASE;
        u32 s0 = base[b], cb = hist[b];
        u32 r = s0;
        for (u32 qq = s0; qq < s0 + cb; qq++) r += (binned[qq] > c) ? 1u : 0u;
        // emit rank r
        u32 idx = 0xFFFFFFFFu - (u32)(c & 0xFFFFFFFFull);
        float val = __uint_as_float((u32)(c >> 32));
        u32 bi = idx / NCLS;
        u32 lab = idx % NCLS;
        const float* bp = boxes + (size_t)bi * 4;
        float x1 = fminf(fmaxf(bp[0], 0.0f), IMGW_M1);
        float y1 = fminf(fmaxf(bp[1], 0.0f), IMGH_M1);
        float x2 = fminf(fmaxf(bp[2], 0.0f), IMGW_M1);
        float y2 = fminf(fmaxf(bp[3], 0.0f), IMGH_M1);
        rboxes[r * 4 + 0] = x1; rboxes[r * 4 + 1] = y1;
        rboxes[r * 4 + 2] = x2; rboxes[r * 4 + 3] = y2;
        rvals[r] = val;
        rlabel[r] = (int)lab;
        out[TOPK * 5 + r] = (float)lab;
    }
    // eq entries (key == cut): rank by ascending idx, take `need`
    for (u32 j = t; j < m; j += 1024) {
        u32 v = eqI[j];
        u32 rho = 0;
        for (u32 k = 0; k < m; k++) rho += (eqI[k] < v) ? 1u : 0u;  // unique
        if (rho < need) {
            u32 r = nsel + rho;
            float val = __uint_as_float(cut);
            u32 bi = v / NCLS;
            u32 lab = v % NCLS;
            const float* bp = boxes + (size_t)bi * 4;
            float x1 = fminf(fmaxf(bp[0], 0.0f), IMGW_M1);
            float y1 = fminf(fmaxf(bp[1], 0.0f), IMGH_M1);
            float x2 = fminf(fmaxf(bp[2], 0.0f), IMGW_M1);
            float y2 = fminf(fmaxf(bp[3], 0.0f), IMGH_M1);
            rboxes[r * 4 + 0] = x1; rboxes[r * 4 + 1] = y1;
            rboxes[r * 4 + 2] = x2; rboxes[r * 4 + 3] = y2;
            rvals[r] = val;
            rlabel[r] = (int)lab;
            out[TOPK * 5 + r] = (float)lab;
        }
    }
}

// per-class greedy NMS: suppression is exactly class-local because the reference's
// label*4096 offset separates classes by >= 4096-1333 while clipped boxes are <=1333 wide.
__global__ void __launch_bounds__(256) k_nms(const float* __restrict__ rboxes,
                                             const float* __restrict__ rvals,
                                             const int* __restrict__ rlabel,
                                             float* __restrict__ out) {
    int c = blockIdx.x + 1;                     // labels 1..80 (class 0 filtered)
    __shared__ unsigned short mem[TOPK];
    __shared__ unsigned char keepL[TOPK];
    __shared__ u32 ps[256];
    __shared__ u32 mtot;
    int t = threadIdx.x;
    int r0 = t * 16;
    u32 cl = 0;
    for (int r = r0; r < r0 + 16; r++) cl += (rlabel[r] == c) ? 1u : 0u;
    ps[t] = cl;
    __syncthreads();
    if (t == 0) {
        u32 acc = 0;
        for (int q = 0; q < 256; q++) { u32 v = ps[q]; ps[q] = acc; acc += v; }
        mtot = acc;
    }
    __syncthreads();
    u32 base = ps[t];
    for (int r = r0; r < r0 + 16; r++)
        if (rlabel[r] == c) mem[base++] = (unsigned short)r;  // stable: rank-ascending
    u32 m = mtot;
    for (u32 q = t; q < m; q += 256) keepL[q] = 1;
    __syncthreads();

    float off = (float)c * 4096.0f;             // replicate reference's f32 offset rounding
    for (u32 i = 0; i < m; i++) {
        __syncthreads();
        if (!keepL[i]) continue;                // uniform branch
        int ri = mem[i];
        float ix1 = rboxes[ri * 4 + 0] + off, iy1 = rboxes[ri * 4 + 1] + off;
        float ix2 = rboxes[ri * 4 + 2] + off, iy2 = rboxes[ri * 4 + 3] + off;
        float iarea = (ix2 - ix1) * (iy2 - iy1);
        for (u32 jj = i + 1 + t; jj < m; jj += 256) {
            if (!keepL[jj]) continue;
            int rj = mem[jj];
            float jx1 = rboxes[rj * 4 + 0] + off, jy1 = rboxes[rj * 4 + 1] + off;
            float jx2 = rboxes[rj * 4 + 2] + off, jy2 = rboxes[rj * 4 + 3] + off;
            float iw = fmaxf(fminf(ix2, jx2) - fmaxf(ix1, jx1), 0.0f);
            float ih = fmaxf(fminf(iy2, jy2) - fmaxf(iy1, jy1), 0.0f);
            float inter = iw * ih;
            float jarea = (jx2 - jx1) * (jy2 - jy1);
            float iou = inter / (iarea + jarea - inter + 1e-9f);
            if (iou > 0.5f) keepL[jj] = 0;
        }
    }
    __syncthreads();
    for (u32 q = t; q < m; q += 256) {
        int r = mem[q];
        int k = keepL[q];
        out[TOPK * 6 + r] = k ? 1.0f : 0.0f;
        float* d = out + (size_t)r * 5;
        if (k) {
            d[0] = rboxes[r * 4 + 0]; d[1] = rboxes[r * 4 + 1];
            d[2] = rboxes[r * 4 + 2]; d[3] = rboxes[r * 4 + 3];
            d[4] = rvals[r];
        } else {
            d[0] = 0; d[1] = 0; d[2] = 0; d[3] = 0; d[4] = 0;
        }
    }
}

extern "C" void kernel_launch(void* const* d_in, const int* in_sizes, int n_in,
                              void* d_out, int out_size, void* d_ws, size_t ws_size,
                              hipStream_t stream) {
    const float* x = (const float*)d_in[0];
    const float* boxes = (const float*)d_in[1];
    float* out = (float*)d_out;

    u32* W = (u32*)d_ws;
    u32* cnt = W;                                 // 16
    u32* hist1g = W + 16;                         // 576
    u32* hist2 = W + 16 + H1_BINS;                // 65536
    u64* sel = (u64*)(W + 16 + H1_BINS + 65536);  // 4096 u64 (8B aligned)
    u32* candKey = W + 16 + H1_BINS + 65536 + 2 * TOPK;
    u32* candIdx = candKey + MAXCAND;
    u32* eqI = candIdx + MAXCAND;
    float* rboxes = (float*)(eqI + EQCAP);
    float* rvals = rboxes + 4 * TOPK;
    int* rlabel = (int*)(rvals + TOPK);

    const int nzero = 16 + H1_BINS + 65536;       // cnt + hist1g + hist2
    k_zero<<<(nzero + 255) / 256, 256, 0, stream>>>(W, nzero);
    k_cand<<<CAND_GRID, CAND_THREADS, 0, stream>>>(x, candKey, candIdx, cnt);
    k_hist1<<<HIST1_GRID, 256, 0, stream>>>(candKey, cnt, hist1g);
    k_mid<<<1, 1024, 0, stream>>>(candKey, cnt, hist1g, hist2);
    k_collect<<<COLL_GRID, 256, 0, stream>>>(candKey, candIdx, cnt, sel, eqI);
    k_rank<<<1, 1024, 0, stream>>>(sel, eqI, cnt, boxes, rboxes, rvals, rlabel, out);
    k_nms<<<80, 256, 0, stream>>>(rboxes, rvals, rlabel, out);
}